// Round 9
// baseline (11857.105 us; speedup 1.0000x reference)
//
#include <hip/hip_runtime.h>
#include <cstddef>
#include <cstdint>

#define DIM 128
#define NROUNDS 120
#define NNZ_CAP (1 << 20)

typedef _Float16 half8 __attribute__((ext_vector_type(8)));
typedef float f32x4 __attribute__((ext_vector_type(4)));
typedef unsigned long long u64;

__device__ __forceinline__ float sigf(float x) { return 1.f / (1.f + __expf(-x)); }
__device__ __forceinline__ float tanh_fast(float x) { return 2.f / (1.f + __expf(-2.f * x)) - 1.f; }

// ---------------- sparse build (deterministic) ----------------
__global__ void count_nz_kernel(const float* __restrict__ adj, int* __restrict__ row_cnt,
                                int* __restrict__ col_cnt, int ncols) {
  int i = blockIdx.x;
  int j = blockIdx.y * blockDim.x + threadIdx.x;
  bool nz = (j < ncols) && (adj[(size_t)i * ncols + j] != 0.f);
  unsigned long long m = __ballot(nz);
  if ((threadIdx.x & 63) == 0) {
    int c = __popcll(m);
    if (c) atomicAdd(&row_cnt[i], c);
  }
  if (nz) atomicAdd(&col_cnt[j], 1);
}

__global__ void scan_kernel(const int* __restrict__ cnt, int* __restrict__ ptr, int n) {
  __shared__ int sdata[256];
  int t = threadIdx.x;
  int per = (n + 255) / 256;
  int beg = t * per;
  int end = beg + per; if (end > n) end = n;
  int local = 0;
  for (int i = beg; i < end; ++i) local += cnt[i];
  sdata[t] = local;
  __syncthreads();
  for (int off = 1; off < 256; off <<= 1) {
    int v = (t >= off) ? sdata[t - off] : 0;
    __syncthreads();
    sdata[t] += v;
    __syncthreads();
  }
  int run = sdata[t] - local;
  for (int i = beg; i < end; ++i) { ptr[i] = run; run += cnt[i]; }
  if (t == 255) ptr[n] = sdata[255];
}

__global__ __launch_bounds__(64) void fill_csr_kernel(const float* __restrict__ adj,
                                                      const int* __restrict__ row_ptr,
                                                      int* __restrict__ col_idx, int ncols) {
  int row = blockIdx.x;
  int lane = threadIdx.x;
  int base = row_ptr[row];
  int cursor = 0;
  const float* arow = adj + (size_t)row * ncols;
  for (int j0 = 0; j0 < ncols; j0 += 64) {
    int j = j0 + lane;
    bool nz = (j < ncols) && (arow[j] != 0.f);
    u64 m = __ballot(nz);
    int pre = __popcll(m & ((1ull << lane) - 1));
    if (nz) col_idx[base + cursor + pre] = j;
    cursor += __popcll(m);
  }
}

__global__ __launch_bounds__(64) void fill_csc_kernel(const float* __restrict__ adj,
                                                      const int* __restrict__ col_ptr,
                                                      int* __restrict__ row_idx,
                                                      int nrows, int ncols) {
  int c = blockIdx.x * 64 + threadIdx.x;
  if (c >= ncols) return;
  int cur = col_ptr[c];
  for (int i = 0; i < nrows; ++i) {
    if (adj[(size_t)i * ncols + c] != 0.f) row_idx[cur++] = i;
  }
}

// ---------------- weight packing: MFMA 16x16x32 B-fragment order (f16) ----------------
// B[k][n] = W[n][k]; lane L holds n = L&15, k = ks*32 + (L>>4)*8 + j (j=0..7)
// dst = ((nt*4 + ks)*64 + L)*8 + j, nt = n>>4
__global__ void pack_w_kernel(const float* __restrict__ src, int out_dim,
                              _Float16* __restrict__ dh) {
  int idx = blockIdx.x * 256 + threadIdx.x;
  if (idx >= out_dim * DIM) return;
  int n = idx >> 7, k = idx & 127;
  _Float16 hi = (_Float16)src[idx];
  int nt = n >> 4, ks = k >> 5;
  int L = ((k >> 3) & 3) * 16 + (n & 15);
  int j = k & 7;
  dh[((nt * 4 + ks) * 64 + L) * 8 + j] = hi;
}

// ---------------- init ----------------
__global__ void init_hc_kernel(const int* __restrict__ values, const float* __restrict__ tW,
                               const float* __restrict__ tb, const float* __restrict__ fW,
                               const float* __restrict__ fb, float* __restrict__ h,
                               float* __restrict__ c, int N) {
  int idx = blockIdx.x * blockDim.x + threadIdx.x;
  if (idx >= N * DIM) return;
  int row = idx >> 7, col = idx & (DIM - 1);
  float tv = tW[col] + tb[col];
  float fv = fW[col] + fb[col];
  h[idx] = (values[row] == 1) ? tv : fv;
  c[idx] = 0.f;
}

// ---------------- LDS swizzle (16 rows x 128, 8-chunk XOR) ----------------
__device__ __forceinline__ int sw_idx(int m, int k) {
  return (m << 7) + (((((k >> 3) ^ (m & 15))) << 3) | (k & 7));
}

// stage 16 fp32 rows -> split f16 LDS (256 threads: r=tid>>4, 8 floats each)
__device__ __forceinline__ void stage_rows(const float* __restrict__ src, int M, int rb,
                                           _Float16* Sh, _Float16* Sl, int tid) {
  int r = tid >> 4, q = tid & 15;
  int row = rb + r;
  float4 v0, v1;
  if (row < M) {
    const float4* s = (const float4*)(src + (size_t)row * DIM + q * 8);
    v0 = s[0]; v1 = s[1];
  } else {
    v0.x = v0.y = v0.z = v0.w = 0.f; v1 = v0;
  }
  int a = sw_idx(r, q * 8);
  float vv[8] = {v0.x, v0.y, v0.z, v0.w, v1.x, v1.y, v1.z, v1.w};
#pragma unroll
  for (int e = 0; e < 8; ++e) {
    _Float16 hi = (_Float16)vv[e];
    Sh[a + e] = hi;
    Sl[a + e] = (_Float16)(vv[e] - (float)hi);
  }
}

// deterministic binary-SpMM gather of 16 rows (f16 va) -> split f16 LDS (256 threads)
__device__ __forceinline__ void gather_rows(const int* __restrict__ ptr,
                                            const int* __restrict__ nzidx,
                                            const _Float16* __restrict__ va, int M, int rb,
                                            _Float16* Xh, _Float16* Xl, int tid) {
  int r = tid >> 4, seg = tid & 15;
  int row = rb + r;
  float a[8];
#pragma unroll
  for (int e = 0; e < 8; ++e) a[e] = 0.f;
  if (row < M) {
    int s = ptr[row], e_ = ptr[row + 1];
    int p = s;
    for (; p + 4 <= e_; p += 4) {
      int i0 = nzidx[p], i1 = nzidx[p + 1], i2 = nzidx[p + 2], i3 = nzidx[p + 3];
      half8 v0 = *(const half8*)(va + (size_t)i0 * DIM + seg * 8);
      half8 v1 = *(const half8*)(va + (size_t)i1 * DIM + seg * 8);
      half8 v2 = *(const half8*)(va + (size_t)i2 * DIM + seg * 8);
      half8 v3 = *(const half8*)(va + (size_t)i3 * DIM + seg * 8);
#pragma unroll
      for (int e = 0; e < 8; ++e)
        a[e] += ((float)v0[e] + (float)v1[e]) + ((float)v2[e] + (float)v3[e]);
    }
    for (; p < e_; ++p) {
      half8 v = *(const half8*)(va + (size_t)nzidx[p] * DIM + seg * 8);
#pragma unroll
      for (int e = 0; e < 8; ++e) a[e] += (float)v[e];
    }
  }
  int aoff = sw_idx(r, seg * 8);
#pragma unroll
  for (int e = 0; e < 8; ++e) {
    _Float16 hi = (_Float16)a[e];
    Xh[aoff + e] = hi;
    Xl[aoff + e] = (_Float16)(a[e] - (float)hi);
  }
}

// split-A x f16-B: 2 MFMAs per product
__device__ __forceinline__ void mfma2(f32x4& acc, half8 ah, half8 al, half8 bh) {
  acc = __builtin_amdgcn_mfma_f32_16x16x32_f16(ah, bh, acc, 0, 0, 0);
  acc = __builtin_amdgcn_mfma_f32_16x16x32_f16(al, bh, acc, 0, 0, 0);
}

// one MLP layer: 16 rows, 4 waves; wave w owns col tiles {2w, 2w+1}
__device__ __forceinline__ void mlp_layer(const _Float16* Ah_, const _Float16* Al_,
                                          const _Float16* __restrict__ Wh,
                                          const float* __restrict__ B,
                                          _Float16* Dh, _Float16* Dl, int tid) {
  int lane = tid & 63, w = tid >> 6;
  int m16 = lane & 15, quad = lane >> 4;
  f32x4 acc[2];
#pragma unroll
  for (int c2 = 0; c2 < 2; ++c2) {
    float bv = B[w * 32 + c2 * 16 + m16];
    acc[c2] = (f32x4){bv, bv, bv, bv};
  }
#pragma unroll
  for (int ks = 0; ks < 4; ++ks) {
    int a_off = sw_idx(m16, ks * 32 + quad * 8);
    half8 ah = *(const half8*)(Ah_ + a_off);
    half8 al = *(const half8*)(Al_ + a_off);
#pragma unroll
    for (int c2 = 0; c2 < 2; ++c2) {
      int ct = w * 2 + c2;
      int boff = ((ct * 4 + ks) * 64 + lane) * 8;
      mfma2(acc[c2], ah, al, *(const half8*)(Wh + boff));
    }
  }
#pragma unroll
  for (int c2 = 0; c2 < 2; ++c2)
#pragma unroll
    for (int reg = 0; reg < 4; ++reg) {
      int rl = quad * 4 + reg;
      int col = w * 32 + c2 * 16 + m16;
      float x = fmaxf(acc[c2][reg], 0.f);
      _Float16 hi = (_Float16)x;
      int a = sw_idx(rl, col);
      Dh[a] = hi;
      Dl[a] = (_Float16)(x - (float)hi);
    }
  __syncthreads();
}

// full 3-layer MLP from LDS input S0/S1; scratch S2/S3; final -> f16 global
__device__ __forceinline__ void mlp_from_lds(
    _Float16* S0, _Float16* S1, _Float16* S2, _Float16* S3, int M, int rb,
    const _Float16* __restrict__ W1h, const float* __restrict__ b1,
    const _Float16* __restrict__ W2h, const float* __restrict__ b2,
    const _Float16* __restrict__ W3h, const float* __restrict__ b3,
    _Float16* __restrict__ out) {
  int tid = threadIdx.x;
  mlp_layer(S0, S1, W1h, b1, S2, S3, tid);
  mlp_layer(S2, S3, W2h, b2, S0, S1, tid);
  int lane = tid & 63, w = tid >> 6;
  int m16 = lane & 15, quad = lane >> 4;
  f32x4 acc[2];
#pragma unroll
  for (int c2 = 0; c2 < 2; ++c2) {
    float bv = b3[w * 32 + c2 * 16 + m16];
    acc[c2] = (f32x4){bv, bv, bv, bv};
  }
#pragma unroll
  for (int ks = 0; ks < 4; ++ks) {
    int a_off = sw_idx(m16, ks * 32 + quad * 8);
    half8 ah = *(const half8*)(S0 + a_off);
    half8 al = *(const half8*)(S1 + a_off);
#pragma unroll
    for (int c2 = 0; c2 < 2; ++c2) {
      int ct = w * 2 + c2;
      int boff = ((ct * 4 + ks) * 64 + lane) * 8;
      mfma2(acc[c2], ah, al, *(const half8*)(W3h + boff));
    }
  }
#pragma unroll
  for (int c2 = 0; c2 < 2; ++c2)
#pragma unroll
    for (int reg = 0; reg < 4; ++reg) {
      int row = rb + quad * 4 + reg;
      int col = w * 32 + c2 * 16 + m16;
      if (row < M) out[(size_t)row * DIM + col] = (_Float16)acc[c2][reg];
    }
}

// ---------------- standalone MLP (initial phase A): global h -> f16 va ----------------
__global__ __launch_bounds__(256, 4) void mlp3_mfma(
    const float* __restrict__ X, int M,
    const _Float16* __restrict__ W1h, const float* __restrict__ b1,
    const _Float16* __restrict__ W2h, const float* __restrict__ b2,
    const _Float16* __restrict__ W3h, const float* __restrict__ b3,
    _Float16* __restrict__ out) {
  __shared__ _Float16 S0[2048], S1[2048], S2[2048], S3[2048];
  int tid = threadIdx.x;
  int rb = blockIdx.x << 4;
  stage_rows(X, M, rb, S0, S1, tid);
  __syncthreads();
  mlp_from_lds(S0, S1, S2, S3, M, rb, W1h, b1, W2h, b2, W3h, b3, out);
}

// ---------------- fused LSTM (+ optional row-local MLP) ----------------
// 256 threads, 16 rows/block; wave w owns col tiles {g*8 + 2w, g*8 + 2w+1} of each gate g
template <bool DO_MLP>
__global__ __launch_bounds__(256, 4) void lstm_fused(
    const int* __restrict__ ptr, const int* __restrict__ nzidx, const _Float16* __restrict__ va_in,
    float* __restrict__ hbuf, float* __restrict__ cbuf, int M,
    const _Float16* __restrict__ Wxh, const _Float16* __restrict__ Whh_,
    const float* __restrict__ bih, const float* __restrict__ bhh,
    const _Float16* __restrict__ W1h, const float* __restrict__ b1,
    const _Float16* __restrict__ W2h, const float* __restrict__ b2,
    const _Float16* __restrict__ W3h, const float* __restrict__ b3,
    _Float16* __restrict__ va_out) {
  __shared__ _Float16 Xh[2048], Xl[2048], Hh[2048], Hl[2048];
  int tid = threadIdx.x;
  int rb = blockIdx.x << 4;
  stage_rows(hbuf, M, rb, Hh, Hl, tid);
  gather_rows(ptr, nzidx, va_in, M, rb, Xh, Xl, tid);
  __syncthreads();

  int lane = tid & 63, w = tid >> 6;
  int m16 = lane & 15, quad = lane >> 4;
  f32x4 acc[2][4];
#pragma unroll
  for (int g = 0; g < 4; ++g)
#pragma unroll
    for (int c2 = 0; c2 < 2; ++c2) {
      int col = g * 128 + w * 32 + c2 * 16 + m16;
      float bv = bih[col] + bhh[col];
      acc[c2][g] = (f32x4){bv, bv, bv, bv};
    }
  // H @ Whh^T
#pragma unroll
  for (int ks = 0; ks < 4; ++ks) {
    int a_off = sw_idx(m16, ks * 32 + quad * 8);
    half8 ah = *(const half8*)(Hh + a_off);
    half8 al = *(const half8*)(Hl + a_off);
#pragma unroll
    for (int g = 0; g < 4; ++g)
#pragma unroll
      for (int c2 = 0; c2 < 2; ++c2) {
        int ct = g * 8 + w * 2 + c2;
        int boff = ((ct * 4 + ks) * 64 + lane) * 8;
        mfma2(acc[c2][g], ah, al, *(const half8*)(Whh_ + boff));
      }
  }
  // X @ Wih^T
#pragma unroll
  for (int ks = 0; ks < 4; ++ks) {
    int a_off = sw_idx(m16, ks * 32 + quad * 8);
    half8 ah = *(const half8*)(Xh + a_off);
    half8 al = *(const half8*)(Xl + a_off);
#pragma unroll
    for (int g = 0; g < 4; ++g)
#pragma unroll
      for (int c2 = 0; c2 < 2; ++c2) {
        int ct = g * 8 + w * 2 + c2;
        int boff = ((ct * 4 + ks) * 64 + lane) * 8;
        mfma2(acc[c2][g], ah, al, *(const half8*)(Wxh + boff));
      }
  }

  if (DO_MLP) __syncthreads();  // all waves done reading Xh/Xl/Hh/Hl before overwrite

  // elementwise epilogue (gate order i,f,g,o); h,c -> global; h_new -> LDS (A-layout)
#pragma unroll
  for (int c2 = 0; c2 < 2; ++c2)
#pragma unroll
    for (int reg = 0; reg < 4; ++reg) {
      int rl = quad * 4 + reg;
      int row = rb + rl;
      int col = w * 32 + c2 * 16 + m16;
      float hn = 0.f;
      if (row < M) {
        float iv = sigf(acc[c2][0][reg]);
        float fv = sigf(acc[c2][1][reg]);
        float gv = tanh_fast(acc[c2][2][reg]);
        float ov = sigf(acc[c2][3][reg]);
        size_t o = (size_t)row * DIM + col;
        float cn = fv * cbuf[o] + iv * gv;
        cbuf[o] = cn;
        hn = ov * tanh_fast(cn);
        hbuf[o] = hn;
      }
      if (DO_MLP) {
        int a = sw_idx(rl, col);
        _Float16 hi = (_Float16)hn;
        Xh[a] = hi;
        Xl[a] = (_Float16)(hn - (float)hi);
      }
    }
  if (DO_MLP) {
    __syncthreads();
    mlp_from_lds(Xh, Xl, Hh, Hl, M, rb, W1h, b1, W2h, b2, W3h, b3, va_out);
  }
}

// ---------------- final vote MLP (fp32, runs once) ----------------
__device__ __forceinline__ void tile_gemm(const float* S, const float* __restrict__ W,
                                          int colB, int rowB, float acc[4][4]) {
#pragma unroll 4
  for (int kc = 0; kc < DIM; kc += 4) {
    float4 xv[4], wv[4];
#pragma unroll
    for (int r = 0; r < 4; ++r) xv[r] = *(const float4*)(S + (rowB + r) * DIM + kc);
#pragma unroll
    for (int c = 0; c < 4; ++c) wv[c] = *(const float4*)(W + (size_t)(colB + c) * DIM + kc);
#pragma unroll
    for (int r = 0; r < 4; ++r)
#pragma unroll
      for (int c = 0; c < 4; ++c)
        acc[r][c] += xv[r].x * wv[c].x + xv[r].y * wv[c].y + xv[r].z * wv[c].z + xv[r].w * wv[c].w;
  }
}

__device__ __forceinline__ void layer_lds(const float* Sin, float* Sout,
                                          const float* __restrict__ W, const float* __restrict__ B,
                                          bool relu, int colB, int rowB) {
  float acc[4][4];
#pragma unroll
  for (int r = 0; r < 4; ++r)
#pragma unroll
    for (int cc = 0; cc < 4; ++cc) acc[r][cc] = B[colB + cc];
  tile_gemm(Sin, W, colB, rowB, acc);
#pragma unroll
  for (int r = 0; r < 4; ++r) {
    float4 v;
    v.x = acc[r][0]; v.y = acc[r][1]; v.z = acc[r][2]; v.w = acc[r][3];
    if (relu) { v.x = fmaxf(v.x, 0.f); v.y = fmaxf(v.y, 0.f); v.z = fmaxf(v.z, 0.f); v.w = fmaxf(v.w, 0.f); }
    *(float4*)&Sout[(rowB + r) * DIM + colB] = v;
  }
  __syncthreads();
}

__global__ __launch_bounds__(256) void vote_kernel(
    const float* __restrict__ X, int M,
    const float* __restrict__ W1, const float* __restrict__ b1,
    const float* __restrict__ W2, const float* __restrict__ b2,
    const float* __restrict__ W3, const float* __restrict__ b3,
    float* __restrict__ out) {
  __shared__ float Xs[32 * DIM];
  __shared__ float Ys[32 * DIM];
  int tid = threadIdx.x;
  int rb = blockIdx.x * 32;
  int mrows = M - rb; if (mrows > 32) mrows = 32;
  {
    const float4* src = (const float4*)(X + (size_t)rb * DIM);
    float4* dst = (float4*)Xs;
    int nf4 = mrows * (DIM / 4);
    for (int t = tid; t < 32 * (DIM / 4); t += 256) {
      float4 v;
      if (t < nf4) v = src[t];
      else { v.x = v.y = v.z = v.w = 0.f; }
      dst[t] = v;
    }
  }
  __syncthreads();
  int tx = tid & 31, ty = tid >> 5;
  int colB = tx * 4, rowB = ty * 4;
  layer_lds(Xs, Ys, W1, b1, true, colB, rowB);
  layer_lds(Ys, Xs, W2, b2, true, colB, rowB);
  if (tid < 32) {
    int gr = rb + tid;
    if (gr < M) {
      float s = b3[0];
      for (int k = 0; k < DIM; ++k) s += Xs[tid * DIM + k] * W3[k];
      out[gr] = s;
    }
  }
}

#define SZ128 (DIM * DIM)
#define SZ512 (4 * DIM * DIM)
#define O_CM1 0
#define O_CM2 (SZ128)
#define O_CM3 (2 * SZ128)
#define O_PM1 (3 * SZ128)
#define O_PM2 (4 * SZ128)
#define O_PM3 (5 * SZ128)
#define O_VUX ((size_t)6 * SZ128)
#define O_VUH ((size_t)6 * SZ128 + SZ512)
#define O_NUX ((size_t)6 * SZ128 + 2 * SZ512)
#define O_NUH ((size_t)6 * SZ128 + 3 * SZ512)

extern "C" void kernel_launch(void* const* d_in, const int* in_sizes, int n_in,
                              void* d_out, int out_size, void* d_ws, size_t ws_size,
                              hipStream_t stream) {
  const float* adj    = (const float*)d_in[0];
  const int*   values = (const int*)d_in[1];
  const int N       = in_sizes[1];                  // 9000
  const int n_nodes = in_sizes[0] / N;              // 8000
  const int n_vars  = N - n_nodes;                  // 1000

  const float* true_W  = (const float*)d_in[3];
  const float* true_b  = (const float*)d_in[4];
  const float* false_W = (const float*)d_in[5];
  const float* false_b = (const float*)d_in[6];
  const float* cm_W1 = (const float*)d_in[7];
  const float* cm_b1 = (const float*)d_in[8];
  const float* cm_W2 = (const float*)d_in[9];
  const float* cm_b2 = (const float*)d_in[10];
  const float* cm_W3 = (const float*)d_in[11];
  const float* cm_b3 = (const float*)d_in[12];
  const float* pm_W1 = (const float*)d_in[13];
  const float* pm_b1 = (const float*)d_in[14];
  const float* pm_W2 = (const float*)d_in[15];
  const float* pm_b2 = (const float*)d_in[16];
  const float* pm_W3 = (const float*)d_in[17];
  const float* pm_b3 = (const float*)d_in[18];
  const float* vv_W1 = (const float*)d_in[19];
  const float* vv_b1 = (const float*)d_in[20];
  const float* vv_W2 = (const float*)d_in[21];
  const float* vv_b2 = (const float*)d_in[22];
  const float* vv_W3 = (const float*)d_in[23];
  const float* vv_b3 = (const float*)d_in[24];
  const float* vu_Wih = (const float*)d_in[25];
  const float* vu_Whh = (const float*)d_in[26];
  const float* vu_bih = (const float*)d_in[27];
  const float* vu_bhh = (const float*)d_in[28];
  const float* nu_Wih = (const float*)d_in[29];
  const float* nu_Whh = (const float*)d_in[30];
  const float* nu_bih = (const float*)d_in[31];
  const float* nu_bhh = (const float*)d_in[32];

  uintptr_t p = (uintptr_t)d_ws;
  auto take = [&](size_t bytes) -> void* {
    uintptr_t cur = (p + 255) & ~(uintptr_t)255;
    p = cur + bytes;
    return (void*)cur;
  };
  float* h   = (float*)take((size_t)N * DIM * sizeof(float));
  float* cb  = (float*)take((size_t)N * DIM * sizeof(float));
  _Float16* va1 = (_Float16*)take((size_t)N * DIM * sizeof(_Float16));
  _Float16* va2 = (_Float16*)take((size_t)N * DIM * sizeof(_Float16));
  int* row_ptr = (int*)take((size_t)(n_nodes + 1) * sizeof(int));
  int* col_ptr = (int*)take((size_t)(N + 1) * sizeof(int));
  int* cnts    = (int*)take((size_t)(n_nodes + N) * sizeof(int));
  int* row_cnt = cnts;
  int* col_cnt = cnts + n_nodes;
  int* col_idx = (int*)take((size_t)NNZ_CAP * sizeof(int));
  int* row_idx = (int*)take((size_t)NNZ_CAP * sizeof(int));

  size_t tot_pack = (size_t)6 * SZ128 + (size_t)4 * SZ512;
  _Float16* packh = (_Float16*)take(tot_pack * sizeof(_Float16));

  hipMemsetAsync(cnts, 0, (size_t)(n_nodes + N) * sizeof(int), stream);
  dim3 cgrid(n_nodes, (N + 255) / 256);
  count_nz_kernel<<<cgrid, 256, 0, stream>>>(adj, row_cnt, col_cnt, N);
  scan_kernel<<<1, 256, 0, stream>>>(row_cnt, row_ptr, n_nodes);
  scan_kernel<<<1, 256, 0, stream>>>(col_cnt, col_ptr, N);
  fill_csr_kernel<<<n_nodes, 64, 0, stream>>>(adj, row_ptr, col_idx, N);
  fill_csc_kernel<<<(N + 63) / 64, 64, 0, stream>>>(adj, col_ptr, row_idx, n_nodes, N);
  init_hc_kernel<<<(N * DIM + 255) / 256, 256, 0, stream>>>(values, true_W, true_b,
                                                            false_W, false_b, h, cb, N);

  auto pack = [&](const float* src, int out_dim, size_t o) {
    pack_w_kernel<<<(out_dim * DIM + 255) / 256, 256, 0, stream>>>(src, out_dim, packh + o);
  };
  pack(cm_W1, DIM, O_CM1); pack(cm_W2, DIM, O_CM2); pack(cm_W3, DIM, O_CM3);
  pack(pm_W1, DIM, O_PM1); pack(pm_W2, DIM, O_PM2); pack(pm_W3, DIM, O_PM3);
  pack(vu_Wih, 4 * DIM, O_VUX); pack(vu_Whh, 4 * DIM, O_VUH);
  pack(nu_Wih, 4 * DIM, O_NUX); pack(nu_Whh, 4 * DIM, O_NUH);

  int tiles_N = (N + 15) / 16, tiles_n = (n_nodes + 15) / 16;

  // A0: var_pre = cm_mlp(h) -> va1 (f16)
  mlp3_mfma<<<tiles_N, 256, 0, stream>>>(h, N,
      packh + O_CM1, cm_b1, packh + O_CM2, cm_b2, packh + O_CM3, cm_b3, va1);

  for (int r = 0; r < NROUNDS; ++r) {
    // B+C: vu-LSTM(csr-gather va1) on rows<n_nodes, then pm-MLP(h_new) -> va2
    lstm_fused<true><<<tiles_n, 256, 0, stream>>>(row_ptr, col_idx, va1, h, cb, n_nodes,
        packh + O_VUX, packh + O_VUH, vu_bih, vu_bhh,
        packh + O_PM1, pm_b1, packh + O_PM2, pm_b2, packh + O_PM3, pm_b3, va2);
    if (r + 1 < NROUNDS) {
      // D+A(next): nu-LSTM(csc-gather va2) on all N rows, then cm-MLP(h_new) -> va1
      lstm_fused<true><<<tiles_N, 256, 0, stream>>>(col_ptr, row_idx, va2, h, cb, N,
          packh + O_NUX, packh + O_NUH, nu_bih, nu_bhh,
          packh + O_CM1, cm_b1, packh + O_CM2, cm_b2, packh + O_CM3, cm_b3, va1);
    } else {
      // final D: nu-LSTM only
      lstm_fused<false><<<tiles_N, 256, 0, stream>>>(col_ptr, row_idx, va2, h, cb, N,
          packh + O_NUX, packh + O_NUH, nu_bih, nu_bhh,
          packh + O_CM1, cm_b1, packh + O_CM2, cm_b2, packh + O_CM3, cm_b3, va1);
    }
  }

  vote_kernel<<<(n_vars + 31) / 32, 256, 0, stream>>>(h + (size_t)n_nodes * DIM, n_vars,
      vv_W1, vv_b1, vv_W2, vv_b2, vv_W3, vv_b3, (float*)d_out);
}

// Round 10
// 10229.254 us; speedup vs baseline: 1.1591x; 1.1591x over previous
//
#include <hip/hip_runtime.h>
#include <cstddef>
#include <cstdint>

#define DIM 128
#define NROUNDS 120
#define NNZ_CAP (1 << 20)

typedef _Float16 half8 __attribute__((ext_vector_type(8)));
typedef float f32x4 __attribute__((ext_vector_type(4)));
typedef unsigned long long u64;

__device__ __forceinline__ float sigf(float x) { return 1.f / (1.f + __expf(-x)); }
__device__ __forceinline__ float tanh_fast(float x) { return 2.f / (1.f + __expf(-2.f * x)) - 1.f; }

// ---------------- sparse build (deterministic) ----------------
__global__ void count_nz_kernel(const float* __restrict__ adj, int* __restrict__ row_cnt,
                                int* __restrict__ col_cnt, int ncols) {
  int i = blockIdx.x;
  int j = blockIdx.y * blockDim.x + threadIdx.x;
  bool nz = (j < ncols) && (adj[(size_t)i * ncols + j] != 0.f);
  unsigned long long m = __ballot(nz);
  if ((threadIdx.x & 63) == 0) {
    int c = __popcll(m);
    if (c) atomicAdd(&row_cnt[i], c);
  }
  if (nz) atomicAdd(&col_cnt[j], 1);
}

__global__ void scan_kernel(const int* __restrict__ cnt, int* __restrict__ ptr, int n) {
  __shared__ int sdata[256];
  int t = threadIdx.x;
  int per = (n + 255) / 256;
  int beg = t * per;
  int end = beg + per; if (end > n) end = n;
  int local = 0;
  for (int i = beg; i < end; ++i) local += cnt[i];
  sdata[t] = local;
  __syncthreads();
  for (int off = 1; off < 256; off <<= 1) {
    int v = (t >= off) ? sdata[t - off] : 0;
    __syncthreads();
    sdata[t] += v;
    __syncthreads();
  }
  int run = sdata[t] - local;
  for (int i = beg; i < end; ++i) { ptr[i] = run; run += cnt[i]; }
  if (t == 255) ptr[n] = sdata[255];
}

__global__ __launch_bounds__(64) void fill_csr_kernel(const float* __restrict__ adj,
                                                      const int* __restrict__ row_ptr,
                                                      int* __restrict__ col_idx, int ncols) {
  int row = blockIdx.x;
  int lane = threadIdx.x;
  int base = row_ptr[row];
  int cursor = 0;
  const float* arow = adj + (size_t)row * ncols;
  for (int j0 = 0; j0 < ncols; j0 += 64) {
    int j = j0 + lane;
    bool nz = (j < ncols) && (arow[j] != 0.f);
    u64 m = __ballot(nz);
    int pre = __popcll(m & ((1ull << lane) - 1));
    if (nz) col_idx[base + cursor + pre] = j;
    cursor += __popcll(m);
  }
}

__global__ __launch_bounds__(64) void fill_csc_kernel(const float* __restrict__ adj,
                                                      const int* __restrict__ col_ptr,
                                                      int* __restrict__ row_idx,
                                                      int nrows, int ncols) {
  int c = blockIdx.x * 64 + threadIdx.x;
  if (c >= ncols) return;
  int cur = col_ptr[c];
  for (int i = 0; i < nrows; ++i) {
    if (adj[(size_t)i * ncols + c] != 0.f) row_idx[cur++] = i;
  }
}

// ---------------- weight packing: MFMA 16x16x32 B-fragment order (f16 only) ----------------
// B[k][n] = W[n][k]; lane L holds n = L&15, k = ks*32 + (L>>4)*8 + j (j=0..7)
// dst = ((nt*4 + ks)*64 + L)*8 + j, nt = n>>4
__global__ void pack_w_kernel(const float* __restrict__ src, int out_dim,
                              _Float16* __restrict__ dh) {
  int idx = blockIdx.x * 256 + threadIdx.x;
  if (idx >= out_dim * DIM) return;
  int n = idx >> 7, k = idx & 127;
  _Float16 hi = (_Float16)src[idx];
  int nt = n >> 4, ks = k >> 5;
  int L = ((k >> 3) & 3) * 16 + (n & 15);
  int j = k & 7;
  dh[((nt * 4 + ks) * 64 + L) * 8 + j] = hi;
}

__global__ void pack_bias_kernel(const float* __restrict__ a, const float* __restrict__ b,
                                 float* __restrict__ o, int n) {
  int i = blockIdx.x * 256 + threadIdx.x;
  if (i < n) o[i] = a[i] + b[i];
}

// ---------------- init ----------------
__global__ void init_hc_kernel(const int* __restrict__ values, const float* __restrict__ tW,
                               const float* __restrict__ tb, const float* __restrict__ fW,
                               const float* __restrict__ fb, float* __restrict__ h,
                               float* __restrict__ c, int N) {
  int idx = blockIdx.x * blockDim.x + threadIdx.x;
  if (idx >= N * DIM) return;
  int row = idx >> 7, col = idx & (DIM - 1);
  float tv = tW[col] + tb[col];
  float fv = fW[col] + fb[col];
  h[idx] = (values[row] == 1) ? tv : fv;
  c[idx] = 0.f;
}

// ---------------- LDS swizzle (32 rows x 128, 8-chunk XOR) ----------------
__device__ __forceinline__ int sw_idx(int m, int k) {
  return (m << 7) + (((((k >> 3) ^ (m & 15))) << 3) | (k & 7));
}

// stage 32 fp32 rows -> split f16 LDS (512 threads: r=tid>>4, 8 floats each)
__device__ __forceinline__ void stage_rows(const float* __restrict__ src, int M, int rb,
                                           _Float16* Sh, _Float16* Sl, int tid) {
  int r = tid >> 4, q = tid & 15;
  int row = rb + r;
  float4 v0, v1;
  if (row < M) {
    const float4* s = (const float4*)(src + (size_t)row * DIM + q * 8);
    v0 = s[0]; v1 = s[1];
  } else {
    v0.x = v0.y = v0.z = v0.w = 0.f; v1 = v0;
  }
  int a = sw_idx(r, q * 8);
  float vv[8] = {v0.x, v0.y, v0.z, v0.w, v1.x, v1.y, v1.z, v1.w};
#pragma unroll
  for (int e = 0; e < 8; ++e) {
    _Float16 hi = (_Float16)vv[e];
    Sh[a + e] = hi;
    Sl[a + e] = (_Float16)(vv[e] - (float)hi);
  }
}

// deterministic binary-SpMM gather of 32 rows (f16 va) -> split f16 LDS (512 threads)
__device__ __forceinline__ void gather_rows(const int* __restrict__ ptr,
                                            const int* __restrict__ nzidx,
                                            const _Float16* __restrict__ va, int M, int rb,
                                            _Float16* Xh, _Float16* Xl, int tid) {
  int r = tid >> 4, seg = tid & 15;
  int row = rb + r;
  float a[8];
#pragma unroll
  for (int e = 0; e < 8; ++e) a[e] = 0.f;
  if (row < M) {
    int s = ptr[row], e_ = ptr[row + 1];
    int p = s;
    for (; p + 4 <= e_; p += 4) {
      int i0 = nzidx[p], i1 = nzidx[p + 1], i2 = nzidx[p + 2], i3 = nzidx[p + 3];
      half8 v0 = *(const half8*)(va + (size_t)i0 * DIM + seg * 8);
      half8 v1 = *(const half8*)(va + (size_t)i1 * DIM + seg * 8);
      half8 v2 = *(const half8*)(va + (size_t)i2 * DIM + seg * 8);
      half8 v3 = *(const half8*)(va + (size_t)i3 * DIM + seg * 8);
#pragma unroll
      for (int e = 0; e < 8; ++e)
        a[e] += ((float)v0[e] + (float)v1[e]) + ((float)v2[e] + (float)v3[e]);
    }
    for (; p < e_; ++p) {
      half8 v = *(const half8*)(va + (size_t)nzidx[p] * DIM + seg * 8);
#pragma unroll
      for (int e = 0; e < 8; ++e) a[e] += (float)v[e];
    }
  }
  int aoff = sw_idx(r, seg * 8);
#pragma unroll
  for (int e = 0; e < 8; ++e) {
    _Float16 hi = (_Float16)a[e];
    Xh[aoff + e] = hi;
    Xl[aoff + e] = (_Float16)(a[e] - (float)hi);
  }
}

// split-A x f16-B: 2 MFMAs per product
__device__ __forceinline__ void mfma2(f32x4& acc, half8 ah, half8 al, half8 bh) {
  acc = __builtin_amdgcn_mfma_f32_16x16x32_f16(ah, bh, acc, 0, 0, 0);
  acc = __builtin_amdgcn_mfma_f32_16x16x32_f16(al, bh, acc, 0, 0, 0);
}

// one MLP layer: 32 rows, 8 waves; wave w owns col tile ct=w (16 cols), both row-subs
__device__ __forceinline__ void mlp_layer(const _Float16* Ah_, const _Float16* Al_,
                                          const _Float16* __restrict__ Wh,
                                          const float* __restrict__ B,
                                          _Float16* Dh, _Float16* Dl, int tid) {
  int lane = tid & 63, w = tid >> 6;
  int m16 = lane & 15, quad = lane >> 4;
  float bv = B[w * 16 + m16];
  f32x4 acc[2];
  acc[0] = (f32x4){bv, bv, bv, bv};
  acc[1] = acc[0];
#pragma unroll
  for (int ks = 0; ks < 4; ++ks) {
    int boff = ((w * 4 + ks) * 64 + lane) * 8;
    half8 bh = *(const half8*)(Wh + boff);
#pragma unroll
    for (int sub = 0; sub < 2; ++sub) {
      int a_off = sw_idx(sub * 16 + m16, ks * 32 + quad * 8);
      mfma2(acc[sub], *(const half8*)(Ah_ + a_off), *(const half8*)(Al_ + a_off), bh);
    }
  }
#pragma unroll
  for (int sub = 0; sub < 2; ++sub)
#pragma unroll
    for (int reg = 0; reg < 4; ++reg) {
      int rl = sub * 16 + quad * 4 + reg;
      int col = w * 16 + m16;
      float x = fmaxf(acc[sub][reg], 0.f);
      _Float16 hi = (_Float16)x;
      int a = sw_idx(rl, col);
      Dh[a] = hi;
      Dl[a] = (_Float16)(x - (float)hi);
    }
  __syncthreads();
}

// full 3-layer MLP from LDS input S0/S1; scratch S2/S3; final -> f16 global
__device__ __forceinline__ void mlp_from_lds(
    _Float16* S0, _Float16* S1, _Float16* S2, _Float16* S3, int M, int rb,
    const _Float16* __restrict__ W1h, const float* __restrict__ b1,
    const _Float16* __restrict__ W2h, const float* __restrict__ b2,
    const _Float16* __restrict__ W3h, const float* __restrict__ b3,
    _Float16* __restrict__ out) {
  int tid = threadIdx.x;
  mlp_layer(S0, S1, W1h, b1, S2, S3, tid);
  mlp_layer(S2, S3, W2h, b2, S0, S1, tid);
  int lane = tid & 63, w = tid >> 6;
  int m16 = lane & 15, quad = lane >> 4;
  float bv = b3[w * 16 + m16];
  f32x4 acc[2];
  acc[0] = (f32x4){bv, bv, bv, bv};
  acc[1] = acc[0];
#pragma unroll
  for (int ks = 0; ks < 4; ++ks) {
    int boff = ((w * 4 + ks) * 64 + lane) * 8;
    half8 bh = *(const half8*)(W3h + boff);
#pragma unroll
    for (int sub = 0; sub < 2; ++sub) {
      int a_off = sw_idx(sub * 16 + m16, ks * 32 + quad * 8);
      mfma2(acc[sub], *(const half8*)(S0 + a_off), *(const half8*)(S1 + a_off), bh);
    }
  }
#pragma unroll
  for (int sub = 0; sub < 2; ++sub)
#pragma unroll
    for (int reg = 0; reg < 4; ++reg) {
      int row = rb + sub * 16 + quad * 4 + reg;
      int col = w * 16 + m16;
      if (row < M) out[(size_t)row * DIM + col] = (_Float16)acc[sub][reg];
    }
}

// ---------------- standalone MLP (initial phase A): global h -> f16 va ----------------
__global__ __launch_bounds__(512, 2) void mlp3_mfma(
    const float* __restrict__ X, int M,
    const _Float16* __restrict__ W1h, const float* __restrict__ b1,
    const _Float16* __restrict__ W2h, const float* __restrict__ b2,
    const _Float16* __restrict__ W3h, const float* __restrict__ b3,
    _Float16* __restrict__ out) {
  __shared__ _Float16 S0[4096], S1[4096], S2[4096], S3[4096];
  int tid = threadIdx.x;
  int rb = blockIdx.x << 5;
  stage_rows(X, M, rb, S0, S1, tid);
  __syncthreads();
  mlp_from_lds(S0, S1, S2, S3, M, rb, W1h, b1, W2h, b2, W3h, b3, out);
}

// ---------------- fused LSTM (+ optional row-local MLP) ----------------
// 512 threads, 32 rows/block; wave w owns cols [w*16,w*16+16) of each gate, both row-subs
template <bool DO_MLP>
__global__ __launch_bounds__(512, 2) void lstm_fused(
    const int* __restrict__ ptr, const int* __restrict__ nzidx, const _Float16* __restrict__ va_in,
    float* __restrict__ hbuf, float* __restrict__ cbuf, int M,
    const _Float16* __restrict__ Wxh, const _Float16* __restrict__ Whh_,
    const float* __restrict__ bcomb,
    const _Float16* __restrict__ W1h, const float* __restrict__ b1,
    const _Float16* __restrict__ W2h, const float* __restrict__ b2,
    const _Float16* __restrict__ W3h, const float* __restrict__ b3,
    _Float16* __restrict__ va_out) {
  __shared__ _Float16 Xh[4096], Xl[4096], Hh[4096], Hl[4096];
  int tid = threadIdx.x;
  int rb = blockIdx.x << 5;
  stage_rows(hbuf, M, rb, Hh, Hl, tid);
  gather_rows(ptr, nzidx, va_in, M, rb, Xh, Xl, tid);

  int lane = tid & 63, w = tid >> 6;
  int m16 = lane & 15, quad = lane >> 4;

  // prefetch old c (epilogue operand) early — hides L2/HBM latency under the gemms
  float cold[2][4];
#pragma unroll
  for (int sub = 0; sub < 2; ++sub)
#pragma unroll
    for (int reg = 0; reg < 4; ++reg) {
      int row = rb + sub * 16 + quad * 4 + reg;
      cold[sub][reg] = (row < M) ? cbuf[(size_t)row * DIM + w * 16 + m16] : 0.f;
    }
  __syncthreads();

  f32x4 acc[2][4];
#pragma unroll
  for (int g = 0; g < 4; ++g) {
    float bv = bcomb[g * 128 + w * 16 + m16];
    acc[0][g] = (f32x4){bv, bv, bv, bv};
    acc[1][g] = acc[0][g];
  }
  // H @ Whh^T (B-fragment loaded once, applied to both row-subs)
#pragma unroll
  for (int ks = 0; ks < 4; ++ks) {
#pragma unroll
    for (int g = 0; g < 4; ++g) {
      int ct = g * 8 + w;
      int boff = ((ct * 4 + ks) * 64 + lane) * 8;
      half8 bh = *(const half8*)(Whh_ + boff);
#pragma unroll
      for (int sub = 0; sub < 2; ++sub) {
        int a_off = sw_idx(sub * 16 + m16, ks * 32 + quad * 8);
        mfma2(acc[sub][g], *(const half8*)(Hh + a_off), *(const half8*)(Hl + a_off), bh);
      }
    }
  }
  // X @ Wih^T
#pragma unroll
  for (int ks = 0; ks < 4; ++ks) {
#pragma unroll
    for (int g = 0; g < 4; ++g) {
      int ct = g * 8 + w;
      int boff = ((ct * 4 + ks) * 64 + lane) * 8;
      half8 bh = *(const half8*)(Wxh + boff);
#pragma unroll
      for (int sub = 0; sub < 2; ++sub) {
        int a_off = sw_idx(sub * 16 + m16, ks * 32 + quad * 8);
        mfma2(acc[sub][g], *(const half8*)(Xh + a_off), *(const half8*)(Xl + a_off), bh);
      }
    }
  }

  if (DO_MLP) __syncthreads();  // all waves done reading Xh/Xl/Hh/Hl before overwrite

  // elementwise epilogue (gate order i,f,g,o); h,c -> global; h_new -> LDS (A-layout)
#pragma unroll
  for (int sub = 0; sub < 2; ++sub)
#pragma unroll
    for (int reg = 0; reg < 4; ++reg) {
      int rl = sub * 16 + quad * 4 + reg;
      int row = rb + rl;
      int col = w * 16 + m16;
      float hn = 0.f;
      if (row < M) {
        float iv = sigf(acc[sub][0][reg]);
        float fv = sigf(acc[sub][1][reg]);
        float gv = tanh_fast(acc[sub][2][reg]);
        float ov = sigf(acc[sub][3][reg]);
        size_t o = (size_t)row * DIM + col;
        float cn = fv * cold[sub][reg] + iv * gv;
        cbuf[o] = cn;
        hn = ov * tanh_fast(cn);
        hbuf[o] = hn;
      }
      if (DO_MLP) {
        int a = sw_idx(rl, col);
        _Float16 hi = (_Float16)hn;
        Xh[a] = hi;
        Xl[a] = (_Float16)(hn - (float)hi);
      }
    }
  if (DO_MLP) {
    __syncthreads();
    mlp_from_lds(Xh, Xl, Hh, Hl, M, rb, W1h, b1, W2h, b2, W3h, b3, va_out);
  }
}

// ---------------- final vote MLP (fp32, runs once) ----------------
__device__ __forceinline__ void tile_gemm(const float* S, const float* __restrict__ W,
                                          int colB, int rowB, float acc[4][4]) {
#pragma unroll 4
  for (int kc = 0; kc < DIM; kc += 4) {
    float4 xv[4], wv[4];
#pragma unroll
    for (int r = 0; r < 4; ++r) xv[r] = *(const float4*)(S + (rowB + r) * DIM + kc);
#pragma unroll
    for (int c = 0; c < 4; ++c) wv[c] = *(const float4*)(W + (size_t)(colB + c) * DIM + kc);
#pragma unroll
    for (int r = 0; r < 4; ++r)
#pragma unroll
      for (int c = 0; c < 4; ++c)
        acc[r][c] += xv[r].x * wv[c].x + xv[r].y * wv[c].y + xv[r].z * wv[c].z + xv[r].w * wv[c].w;
  }
}

__device__ __forceinline__ void layer_lds(const float* Sin, float* Sout,
                                          const float* __restrict__ W, const float* __restrict__ B,
                                          bool relu, int colB, int rowB) {
  float acc[4][4];
#pragma unroll
  for (int r = 0; r < 4; ++r)
#pragma unroll
    for (int cc = 0; cc < 4; ++cc) acc[r][cc] = B[colB + cc];
  tile_gemm(Sin, W, colB, rowB, acc);
#pragma unroll
  for (int r = 0; r < 4; ++r) {
    float4 v;
    v.x = acc[r][0]; v.y = acc[r][1]; v.z = acc[r][2]; v.w = acc[r][3];
    if (relu) { v.x = fmaxf(v.x, 0.f); v.y = fmaxf(v.y, 0.f); v.z = fmaxf(v.z, 0.f); v.w = fmaxf(v.w, 0.f); }
    *(float4*)&Sout[(rowB + r) * DIM + colB] = v;
  }
  __syncthreads();
}

__global__ __launch_bounds__(256) void vote_kernel(
    const float* __restrict__ X, int M,
    const float* __restrict__ W1, const float* __restrict__ b1,
    const float* __restrict__ W2, const float* __restrict__ b2,
    const float* __restrict__ W3, const float* __restrict__ b3,
    float* __restrict__ out) {
  __shared__ float Xs[32 * DIM];
  __shared__ float Ys[32 * DIM];
  int tid = threadIdx.x;
  int rb = blockIdx.x * 32;
  int mrows = M - rb; if (mrows > 32) mrows = 32;
  {
    const float4* src = (const float4*)(X + (size_t)rb * DIM);
    float4* dst = (float4*)Xs;
    int nf4 = mrows * (DIM / 4);
    for (int t = tid; t < 32 * (DIM / 4); t += 256) {
      float4 v;
      if (t < nf4) v = src[t];
      else { v.x = v.y = v.z = v.w = 0.f; }
      dst[t] = v;
    }
  }
  __syncthreads();
  int tx = tid & 31, ty = tid >> 5;
  int colB = tx * 4, rowB = ty * 4;
  layer_lds(Xs, Ys, W1, b1, true, colB, rowB);
  layer_lds(Ys, Xs, W2, b2, true, colB, rowB);
  if (tid < 32) {
    int gr = rb + tid;
    if (gr < M) {
      float s = b3[0];
      for (int k = 0; k < DIM; ++k) s += Xs[tid * DIM + k] * W3[k];
      out[gr] = s;
    }
  }
}

#define SZ128 (DIM * DIM)
#define SZ512 (4 * DIM * DIM)
#define O_CM1 0
#define O_CM2 (SZ128)
#define O_CM3 (2 * SZ128)
#define O_PM1 (3 * SZ128)
#define O_PM2 (4 * SZ128)
#define O_PM3 (5 * SZ128)
#define O_VUX ((size_t)6 * SZ128)
#define O_VUH ((size_t)6 * SZ128 + SZ512)
#define O_NUX ((size_t)6 * SZ128 + 2 * SZ512)
#define O_NUH ((size_t)6 * SZ128 + 3 * SZ512)

extern "C" void kernel_launch(void* const* d_in, const int* in_sizes, int n_in,
                              void* d_out, int out_size, void* d_ws, size_t ws_size,
                              hipStream_t stream) {
  const float* adj    = (const float*)d_in[0];
  const int*   values = (const int*)d_in[1];
  const int N       = in_sizes[1];                  // 9000
  const int n_nodes = in_sizes[0] / N;              // 8000
  const int n_vars  = N - n_nodes;                  // 1000

  const float* true_W  = (const float*)d_in[3];
  const float* true_b  = (const float*)d_in[4];
  const float* false_W = (const float*)d_in[5];
  const float* false_b = (const float*)d_in[6];
  const float* cm_W1 = (const float*)d_in[7];
  const float* cm_b1 = (const float*)d_in[8];
  const float* cm_W2 = (const float*)d_in[9];
  const float* cm_b2 = (const float*)d_in[10];
  const float* cm_W3 = (const float*)d_in[11];
  const float* cm_b3 = (const float*)d_in[12];
  const float* pm_W1 = (const float*)d_in[13];
  const float* pm_b1 = (const float*)d_in[14];
  const float* pm_W2 = (const float*)d_in[15];
  const float* pm_b2 = (const float*)d_in[16];
  const float* pm_W3 = (const float*)d_in[17];
  const float* pm_b3 = (const float*)d_in[18];
  const float* vv_W1 = (const float*)d_in[19];
  const float* vv_b1 = (const float*)d_in[20];
  const float* vv_W2 = (const float*)d_in[21];
  const float* vv_b2 = (const float*)d_in[22];
  const float* vv_W3 = (const float*)d_in[23];
  const float* vv_b3 = (const float*)d_in[24];
  const float* vu_Wih = (const float*)d_in[25];
  const float* vu_Whh = (const float*)d_in[26];
  const float* vu_bih = (const float*)d_in[27];
  const float* vu_bhh = (const float*)d_in[28];
  const float* nu_Wih = (const float*)d_in[29];
  const float* nu_Whh = (const float*)d_in[30];
  const float* nu_bih = (const float*)d_in[31];
  const float* nu_bhh = (const float*)d_in[32];

  uintptr_t p = (uintptr_t)d_ws;
  auto take = [&](size_t bytes) -> void* {
    uintptr_t cur = (p + 255) & ~(uintptr_t)255;
    p = cur + bytes;
    return (void*)cur;
  };
  float* h   = (float*)take((size_t)N * DIM * sizeof(float));
  float* cb  = (float*)take((size_t)N * DIM * sizeof(float));
  _Float16* va1 = (_Float16*)take((size_t)N * DIM * sizeof(_Float16));
  _Float16* va2 = (_Float16*)take((size_t)N * DIM * sizeof(_Float16));
  int* row_ptr = (int*)take((size_t)(n_nodes + 1) * sizeof(int));
  int* col_ptr = (int*)take((size_t)(N + 1) * sizeof(int));
  int* cnts    = (int*)take((size_t)(n_nodes + N) * sizeof(int));
  int* row_cnt = cnts;
  int* col_cnt = cnts + n_nodes;
  int* col_idx = (int*)take((size_t)NNZ_CAP * sizeof(int));
  int* row_idx = (int*)take((size_t)NNZ_CAP * sizeof(int));

  size_t tot_pack = (size_t)6 * SZ128 + (size_t)4 * SZ512;
  _Float16* packh = (_Float16*)take(tot_pack * sizeof(_Float16));
  float* vu_b = (float*)take(512 * sizeof(float));
  float* nu_b = (float*)take(512 * sizeof(float));

  hipMemsetAsync(cnts, 0, (size_t)(n_nodes + N) * sizeof(int), stream);
  dim3 cgrid(n_nodes, (N + 255) / 256);
  count_nz_kernel<<<cgrid, 256, 0, stream>>>(adj, row_cnt, col_cnt, N);
  scan_kernel<<<1, 256, 0, stream>>>(row_cnt, row_ptr, n_nodes);
  scan_kernel<<<1, 256, 0, stream>>>(col_cnt, col_ptr, N);
  fill_csr_kernel<<<n_nodes, 64, 0, stream>>>(adj, row_ptr, col_idx, N);
  fill_csc_kernel<<<(N + 63) / 64, 64, 0, stream>>>(adj, col_ptr, row_idx, n_nodes, N);
  init_hc_kernel<<<(N * DIM + 255) / 256, 256, 0, stream>>>(values, true_W, true_b,
                                                            false_W, false_b, h, cb, N);

  auto pack = [&](const float* src, int out_dim, size_t o) {
    pack_w_kernel<<<(out_dim * DIM + 255) / 256, 256, 0, stream>>>(src, out_dim, packh + o);
  };
  pack(cm_W1, DIM, O_CM1); pack(cm_W2, DIM, O_CM2); pack(cm_W3, DIM, O_CM3);
  pack(pm_W1, DIM, O_PM1); pack(pm_W2, DIM, O_PM2); pack(pm_W3, DIM, O_PM3);
  pack(vu_Wih, 4 * DIM, O_VUX); pack(vu_Whh, 4 * DIM, O_VUH);
  pack(nu_Wih, 4 * DIM, O_NUX); pack(nu_Whh, 4 * DIM, O_NUH);
  pack_bias_kernel<<<2, 256, 0, stream>>>(vu_bih, vu_bhh, vu_b, 512);
  pack_bias_kernel<<<2, 256, 0, stream>>>(nu_bih, nu_bhh, nu_b, 512);

  int tiles_N = (N + 31) / 32, tiles_n = (n_nodes + 31) / 32;

  // A0: var_pre = cm_mlp(h) -> va1 (f16)
  mlp3_mfma<<<tiles_N, 512, 0, stream>>>(h, N,
      packh + O_CM1, cm_b1, packh + O_CM2, cm_b2, packh + O_CM3, cm_b3, va1);

  for (int r = 0; r < NROUNDS; ++r) {
    // B+C: vu-LSTM(csr-gather va1) on rows<n_nodes, then pm-MLP(h_new) -> va2
    lstm_fused<true><<<tiles_n, 512, 0, stream>>>(row_ptr, col_idx, va1, h, cb, n_nodes,
        packh + O_VUX, packh + O_VUH, vu_b,
        packh + O_PM1, pm_b1, packh + O_PM2, pm_b2, packh + O_PM3, pm_b3, va2);
    if (r + 1 < NROUNDS) {
      // D+A(next): nu-LSTM(csc-gather va2) on all N rows, then cm-MLP(h_new) -> va1
      lstm_fused<true><<<tiles_N, 512, 0, stream>>>(col_ptr, row_idx, va2, h, cb, N,
          packh + O_NUX, packh + O_NUH, nu_b,
          packh + O_CM1, cm_b1, packh + O_CM2, cm_b2, packh + O_CM3, cm_b3, va1);
    } else {
      // final D: nu-LSTM only
      lstm_fused<false><<<tiles_N, 512, 0, stream>>>(col_ptr, row_idx, va2, h, cb, N,
          packh + O_NUX, packh + O_NUH, nu_b,
          packh + O_CM1, cm_b1, packh + O_CM2, cm_b2, packh + O_CM3, cm_b3, va1);
    }
  }

  vote_kernel<<<(n_vars + 31) / 32, 256, 0, stream>>>(h + (size_t)n_nodes * DIM, n_vars,
      vv_W1, vv_b1, vv_W2, vv_b2, vv_W3, vv_b3, (float*)d_out);
}

// Round 11
// 10211.664 us; speedup vs baseline: 1.1611x; 1.0017x over previous
//
#include <hip/hip_runtime.h>
#include <cstddef>
#include <cstdint>

#define DIM 128
#define NROUNDS 120
#define NNZ_CAP (1 << 20)

typedef _Float16 half8 __attribute__((ext_vector_type(8)));
typedef float f32x4 __attribute__((ext_vector_type(4)));
typedef unsigned long long u64;

__device__ __forceinline__ float sigf(float x) { return 1.f / (1.f + __expf(-x)); }
__device__ __forceinline__ float tanh_fast(float x) { return 2.f / (1.f + __expf(-2.f * x)) - 1.f; }

// ---------------- sparse build (deterministic) ----------------
__global__ void count_nz_kernel(const float* __restrict__ adj, int* __restrict__ row_cnt,
                                int* __restrict__ col_cnt, int ncols) {
  int i = blockIdx.x;
  int j = blockIdx.y * blockDim.x + threadIdx.x;
  bool nz = (j < ncols) && (adj[(size_t)i * ncols + j] != 0.f);
  unsigned long long m = __ballot(nz);
  if ((threadIdx.x & 63) == 0) {
    int c = __popcll(m);
    if (c) atomicAdd(&row_cnt[i], c);
  }
  if (nz) atomicAdd(&col_cnt[j], 1);
}

__global__ void scan_kernel(const int* __restrict__ cnt, int* __restrict__ ptr, int n) {
  __shared__ int sdata[256];
  int t = threadIdx.x;
  int per = (n + 255) / 256;
  int beg = t * per;
  int end = beg + per; if (end > n) end = n;
  int local = 0;
  for (int i = beg; i < end; ++i) local += cnt[i];
  sdata[t] = local;
  __syncthreads();
  for (int off = 1; off < 256; off <<= 1) {
    int v = (t >= off) ? sdata[t - off] : 0;
    __syncthreads();
    sdata[t] += v;
    __syncthreads();
  }
  int run = sdata[t] - local;
  for (int i = beg; i < end; ++i) { ptr[i] = run; run += cnt[i]; }
  if (t == 255) ptr[n] = sdata[255];
}

__global__ __launch_bounds__(64) void fill_csr_kernel(const float* __restrict__ adj,
                                                      const int* __restrict__ row_ptr,
                                                      int* __restrict__ col_idx, int ncols) {
  int row = blockIdx.x;
  int lane = threadIdx.x;
  int base = row_ptr[row];
  int cursor = 0;
  const float* arow = adj + (size_t)row * ncols;
  for (int j0 = 0; j0 < ncols; j0 += 64) {
    int j = j0 + lane;
    bool nz = (j < ncols) && (arow[j] != 0.f);
    u64 m = __ballot(nz);
    int pre = __popcll(m & ((1ull << lane) - 1));
    if (nz) col_idx[base + cursor + pre] = j;
    cursor += __popcll(m);
  }
}

__global__ __launch_bounds__(64) void fill_csc_kernel(const float* __restrict__ adj,
                                                      const int* __restrict__ col_ptr,
                                                      int* __restrict__ row_idx,
                                                      int nrows, int ncols) {
  int c = blockIdx.x * 64 + threadIdx.x;
  if (c >= ncols) return;
  int cur = col_ptr[c];
  for (int i = 0; i < nrows; ++i) {
    if (adj[(size_t)i * ncols + c] != 0.f) row_idx[cur++] = i;
  }
}

// ---------------- weight packing: MFMA 16x16x32 B-fragment order (f16 only) ----------------
__global__ void pack_w_kernel(const float* __restrict__ src, int out_dim,
                              _Float16* __restrict__ dh) {
  int idx = blockIdx.x * 256 + threadIdx.x;
  if (idx >= out_dim * DIM) return;
  int n = idx >> 7, k = idx & 127;
  _Float16 hi = (_Float16)src[idx];
  int nt = n >> 4, ks = k >> 5;
  int L = ((k >> 3) & 3) * 16 + (n & 15);
  int j = k & 7;
  dh[((nt * 4 + ks) * 64 + L) * 8 + j] = hi;
}

__global__ void pack_bias_kernel(const float* __restrict__ a, const float* __restrict__ b,
                                 float* __restrict__ o, int n) {
  int i = blockIdx.x * 256 + threadIdx.x;
  if (i < n) o[i] = a[i] + b[i];
}

// ---------------- init ----------------
__global__ void init_hc_kernel(const int* __restrict__ values, const float* __restrict__ tW,
                               const float* __restrict__ tb, const float* __restrict__ fW,
                               const float* __restrict__ fb, float* __restrict__ h,
                               float* __restrict__ c, int N) {
  int idx = blockIdx.x * blockDim.x + threadIdx.x;
  if (idx >= N * DIM) return;
  int row = idx >> 7, col = idx & (DIM - 1);
  float tv = tW[col] + tb[col];
  float fv = fW[col] + fb[col];
  h[idx] = (values[row] == 1) ? tv : fv;
  c[idx] = 0.f;
}

// ---------------- LDS swizzle (rows x 128, 8-chunk XOR) ----------------
__device__ __forceinline__ int sw_idx(int m, int k) {
  return (m << 7) + (((((k >> 3) ^ (m & 15))) << 3) | (k & 7));
}

// stage fp32 rows -> split f16 LDS (512 threads; NSUB*16 row slots)
template <int NSUB>
__device__ __forceinline__ void stage_rows_t(const float* __restrict__ src, int rend, int rb,
                                             _Float16* Sh, _Float16* Sl, int tid) {
  int seg = tid & 15;
  for (int r = tid >> 4; r < NSUB * 16; r += 32) {
    int row = rb + r;
    float4 v0, v1;
    if (row < rend) {
      const float4* s = (const float4*)(src + (size_t)row * DIM + seg * 8);
      v0 = s[0]; v1 = s[1];
    } else {
      v0.x = v0.y = v0.z = v0.w = 0.f; v1 = v0;
    }
    int a = sw_idx(r, seg * 8);
    float vv[8] = {v0.x, v0.y, v0.z, v0.w, v1.x, v1.y, v1.z, v1.w};
#pragma unroll
    for (int e = 0; e < 8; ++e) {
      _Float16 hi = (_Float16)vv[e];
      Sh[a + e] = hi;
      Sl[a + e] = (_Float16)(vv[e] - (float)hi);
    }
  }
}

// deterministic binary-SpMM gather (f16 va) -> split f16 LDS; 8-deep load unroll
template <int NSUB>
__device__ __forceinline__ void gather_rows_t(const int* __restrict__ ptr,
                                              const int* __restrict__ nzidx,
                                              const _Float16* __restrict__ va, int rend, int rb,
                                              _Float16* Xh, _Float16* Xl, int tid) {
  int seg = tid & 15;
  for (int r = tid >> 4; r < NSUB * 16; r += 32) {
    int row = rb + r;
    float a[8];
#pragma unroll
    for (int e = 0; e < 8; ++e) a[e] = 0.f;
    if (row < rend) {
      int s = ptr[row], e_ = ptr[row + 1];
      int p = s;
      for (; p + 8 <= e_; p += 8) {
        half8 v0 = *(const half8*)(va + (size_t)nzidx[p] * DIM + seg * 8);
        half8 v1 = *(const half8*)(va + (size_t)nzidx[p + 1] * DIM + seg * 8);
        half8 v2 = *(const half8*)(va + (size_t)nzidx[p + 2] * DIM + seg * 8);
        half8 v3 = *(const half8*)(va + (size_t)nzidx[p + 3] * DIM + seg * 8);
        half8 v4 = *(const half8*)(va + (size_t)nzidx[p + 4] * DIM + seg * 8);
        half8 v5 = *(const half8*)(va + (size_t)nzidx[p + 5] * DIM + seg * 8);
        half8 v6 = *(const half8*)(va + (size_t)nzidx[p + 6] * DIM + seg * 8);
        half8 v7 = *(const half8*)(va + (size_t)nzidx[p + 7] * DIM + seg * 8);
#pragma unroll
        for (int e = 0; e < 8; ++e)
          a[e] += (((float)v0[e] + (float)v1[e]) + ((float)v2[e] + (float)v3[e])) +
                  (((float)v4[e] + (float)v5[e]) + ((float)v6[e] + (float)v7[e]));
      }
      for (; p + 2 <= e_; p += 2) {
        half8 v0 = *(const half8*)(va + (size_t)nzidx[p] * DIM + seg * 8);
        half8 v1 = *(const half8*)(va + (size_t)nzidx[p + 1] * DIM + seg * 8);
#pragma unroll
        for (int e = 0; e < 8; ++e) a[e] += (float)v0[e] + (float)v1[e];
      }
      if (p < e_) {
        half8 v = *(const half8*)(va + (size_t)nzidx[p] * DIM + seg * 8);
#pragma unroll
        for (int e = 0; e < 8; ++e) a[e] += (float)v[e];
      }
    }
    int aoff = sw_idx(r, seg * 8);
#pragma unroll
    for (int e = 0; e < 8; ++e) {
      _Float16 hi = (_Float16)a[e];
      Xh[aoff + e] = hi;
      Xl[aoff + e] = (_Float16)(a[e] - (float)hi);
    }
  }
}

// split-A x f16-B: 2 MFMAs per product
__device__ __forceinline__ void mfma2(f32x4& acc, half8 ah, half8 al, half8 bh) {
  acc = __builtin_amdgcn_mfma_f32_16x16x32_f16(ah, bh, acc, 0, 0, 0);
  acc = __builtin_amdgcn_mfma_f32_16x16x32_f16(al, bh, acc, 0, 0, 0);
}

// one MLP layer: NSUB 16-row subtiles, 8 waves; wave w owns col tile w (16 cols)
template <int NSUB>
__device__ __forceinline__ void mlp_layer_t(const _Float16* Ah_, const _Float16* Al_,
                                            const _Float16* __restrict__ Wh,
                                            const float* __restrict__ B,
                                            _Float16* Dh, _Float16* Dl, int tid) {
  int lane = tid & 63, w = tid >> 6;
  int m16 = lane & 15, quad = lane >> 4;
  float bv = B[w * 16 + m16];
  f32x4 acc[NSUB];
#pragma unroll
  for (int s = 0; s < NSUB; ++s) acc[s] = (f32x4){bv, bv, bv, bv};
#pragma unroll
  for (int ks = 0; ks < 4; ++ks) {
    int boff = ((w * 4 + ks) * 64 + lane) * 8;
    half8 bh = *(const half8*)(Wh + boff);
#pragma unroll
    for (int s = 0; s < NSUB; ++s) {
      int a_off = sw_idx(s * 16 + m16, ks * 32 + quad * 8);
      mfma2(acc[s], *(const half8*)(Ah_ + a_off), *(const half8*)(Al_ + a_off), bh);
    }
  }
#pragma unroll
  for (int s = 0; s < NSUB; ++s)
#pragma unroll
    for (int reg = 0; reg < 4; ++reg) {
      int rl = s * 16 + quad * 4 + reg;
      int col = w * 16 + m16;
      float x = fmaxf(acc[s][reg], 0.f);
      _Float16 hi = (_Float16)x;
      int a = sw_idx(rl, col);
      Dh[a] = hi;
      Dl[a] = (_Float16)(x - (float)hi);
    }
  __syncthreads();
}

// full 3-layer MLP from LDS input S0/S1; scratch S2/S3; final -> f16 global
template <int NSUB>
__device__ __forceinline__ void mlp_from_lds_t(
    _Float16* S0, _Float16* S1, _Float16* S2, _Float16* S3, int rend, int rb,
    const _Float16* __restrict__ W1h, const float* __restrict__ b1,
    const _Float16* __restrict__ W2h, const float* __restrict__ b2,
    const _Float16* __restrict__ W3h, const float* __restrict__ b3,
    _Float16* __restrict__ out) {
  int tid = threadIdx.x;
  mlp_layer_t<NSUB>(S0, S1, W1h, b1, S2, S3, tid);
  mlp_layer_t<NSUB>(S2, S3, W2h, b2, S0, S1, tid);
  int lane = tid & 63, w = tid >> 6;
  int m16 = lane & 15, quad = lane >> 4;
  float bv = b3[w * 16 + m16];
  f32x4 acc[NSUB];
#pragma unroll
  for (int s = 0; s < NSUB; ++s) acc[s] = (f32x4){bv, bv, bv, bv};
#pragma unroll
  for (int ks = 0; ks < 4; ++ks) {
    int boff = ((w * 4 + ks) * 64 + lane) * 8;
    half8 bh = *(const half8*)(W3h + boff);
#pragma unroll
    for (int s = 0; s < NSUB; ++s) {
      int a_off = sw_idx(s * 16 + m16, ks * 32 + quad * 8);
      mfma2(acc[s], *(const half8*)(S0 + a_off), *(const half8*)(S1 + a_off), bh);
    }
  }
#pragma unroll
  for (int s = 0; s < NSUB; ++s)
#pragma unroll
    for (int reg = 0; reg < 4; ++reg) {
      int row = rb + s * 16 + quad * 4 + reg;
      int col = w * 16 + m16;
      if (row < rend) out[(size_t)row * DIM + col] = (_Float16)acc[s][reg];
    }
}

// ---------------- standalone MLP (initial phase A): global h -> f16 va ----------------
template <int NSUB>
__global__ __launch_bounds__(512, 1) void mlp3_mfma(
    const float* __restrict__ X, int M, int rpb,
    const _Float16* __restrict__ W1h, const float* __restrict__ b1,
    const _Float16* __restrict__ W2h, const float* __restrict__ b2,
    const _Float16* __restrict__ W3h, const float* __restrict__ b3,
    _Float16* __restrict__ out) {
  __shared__ _Float16 S0[NSUB * 2048], S1[NSUB * 2048], S2[NSUB * 2048], S3[NSUB * 2048];
  int tid = threadIdx.x;
  int rb = blockIdx.x * rpb;
  int rend = rb + rpb; if (rend > M) rend = M;
  stage_rows_t<NSUB>(X, rend, rb, S0, S1, tid);
  __syncthreads();
  mlp_from_lds_t<NSUB>(S0, S1, S2, S3, rend, rb, W1h, b1, W2h, b2, W3h, b3, out);
}

// ---------------- fused LSTM (+ optional row-local MLP) ----------------
// 512 threads, NSUB*16 row slots (rpb active rows); wave w owns cols [w*16,w*16+16) per gate
template <int NSUB, bool DO_MLP>
__global__ __launch_bounds__(512, 1) void lstm_fused(
    const int* __restrict__ ptr, const int* __restrict__ nzidx, const _Float16* __restrict__ va_in,
    float* __restrict__ hbuf, float* __restrict__ cbuf, int M, int rpb,
    const _Float16* __restrict__ Wxh, const _Float16* __restrict__ Whh_,
    const float* __restrict__ bcomb,
    const _Float16* __restrict__ W1h, const float* __restrict__ b1,
    const _Float16* __restrict__ W2h, const float* __restrict__ b2,
    const _Float16* __restrict__ W3h, const float* __restrict__ b3,
    _Float16* __restrict__ va_out) {
  __shared__ _Float16 Xh[NSUB * 2048], Xl[NSUB * 2048], Hh[NSUB * 2048], Hl[NSUB * 2048];
  int tid = threadIdx.x;
  int rb = blockIdx.x * rpb;
  int rend = rb + rpb; if (rend > M) rend = M;
  stage_rows_t<NSUB>(hbuf, rend, rb, Hh, Hl, tid);
  gather_rows_t<NSUB>(ptr, nzidx, va_in, rend, rb, Xh, Xl, tid);

  int lane = tid & 63, w = tid >> 6;
  int m16 = lane & 15, quad = lane >> 4;

  // prefetch old c early — hides L2/L3 latency under the gemms
  float cold[NSUB][4];
#pragma unroll
  for (int s = 0; s < NSUB; ++s)
#pragma unroll
    for (int reg = 0; reg < 4; ++reg) {
      int row = rb + s * 16 + quad * 4 + reg;
      cold[s][reg] = (row < rend) ? cbuf[(size_t)row * DIM + w * 16 + m16] : 0.f;
    }
  __syncthreads();

  f32x4 acc[NSUB][4];
#pragma unroll
  for (int g = 0; g < 4; ++g) {
    float bv = bcomb[g * 128 + w * 16 + m16];
#pragma unroll
    for (int s = 0; s < NSUB; ++s) acc[s][g] = (f32x4){bv, bv, bv, bv};
  }
  // H @ Whh^T (B fragment loaded once, applied to all subtiles)
#pragma unroll
  for (int ks = 0; ks < 4; ++ks) {
#pragma unroll
    for (int g = 0; g < 4; ++g) {
      int ct = g * 8 + w;
      int boff = ((ct * 4 + ks) * 64 + lane) * 8;
      half8 bh = *(const half8*)(Whh_ + boff);
#pragma unroll
      for (int s = 0; s < NSUB; ++s) {
        int a_off = sw_idx(s * 16 + m16, ks * 32 + quad * 8);
        mfma2(acc[s][g], *(const half8*)(Hh + a_off), *(const half8*)(Hl + a_off), bh);
      }
    }
  }
  // X @ Wih^T
#pragma unroll
  for (int ks = 0; ks < 4; ++ks) {
#pragma unroll
    for (int g = 0; g < 4; ++g) {
      int ct = g * 8 + w;
      int boff = ((ct * 4 + ks) * 64 + lane) * 8;
      half8 bh = *(const half8*)(Wxh + boff);
#pragma unroll
      for (int s = 0; s < NSUB; ++s) {
        int a_off = sw_idx(s * 16 + m16, ks * 32 + quad * 8);
        mfma2(acc[s][g], *(const half8*)(Xh + a_off), *(const half8*)(Xl + a_off), bh);
      }
    }
  }

  if (DO_MLP) __syncthreads();  // all waves done reading Xh/Xl/Hh/Hl before overwrite

  // elementwise epilogue (gate order i,f,g,o); h,c -> global; h_new -> LDS (A-layout)
#pragma unroll
  for (int s = 0; s < NSUB; ++s)
#pragma unroll
    for (int reg = 0; reg < 4; ++reg) {
      int rl = s * 16 + quad * 4 + reg;
      int row = rb + rl;
      int col = w * 16 + m16;
      float hn = 0.f;
      if (row < rend) {
        float iv = sigf(acc[s][0][reg]);
        float fv = sigf(acc[s][1][reg]);
        float gv = tanh_fast(acc[s][2][reg]);
        float ov = sigf(acc[s][3][reg]);
        size_t o = (size_t)row * DIM + col;
        float cn = fv * cold[s][reg] + iv * gv;
        cbuf[o] = cn;
        hn = ov * tanh_fast(cn);
        hbuf[o] = hn;
      }
      if (DO_MLP) {
        int a = sw_idx(rl, col);
        _Float16 hi = (_Float16)hn;
        Xh[a] = hi;
        Xl[a] = (_Float16)(hn - (float)hi);
      }
    }
  if (DO_MLP) {
    __syncthreads();
    mlp_from_lds_t<NSUB>(Xh, Xl, Hh, Hl, rend, rb, W1h, b1, W2h, b2, W3h, b3, va_out);
  }
}

// ---------------- final vote MLP (fp32, runs once) ----------------
__device__ __forceinline__ void tile_gemm(const float* S, const float* __restrict__ W,
                                          int colB, int rowB, float acc[4][4]) {
#pragma unroll 4
  for (int kc = 0; kc < DIM; kc += 4) {
    float4 xv[4], wv[4];
#pragma unroll
    for (int r = 0; r < 4; ++r) xv[r] = *(const float4*)(S + (rowB + r) * DIM + kc);
#pragma unroll
    for (int c = 0; c < 4; ++c) wv[c] = *(const float4*)(W + (size_t)(colB + c) * DIM + kc);
#pragma unroll
    for (int r = 0; r < 4; ++r)
#pragma unroll
      for (int c = 0; c < 4; ++c)
        acc[r][c] += xv[r].x * wv[c].x + xv[r].y * wv[c].y + xv[r].z * wv[c].z + xv[r].w * wv[c].w;
  }
}

__device__ __forceinline__ void layer_lds(const float* Sin, float* Sout,
                                          const float* __restrict__ W, const float* __restrict__ B,
                                          bool relu, int colB, int rowB) {
  float acc[4][4];
#pragma unroll
  for (int r = 0; r < 4; ++r)
#pragma unroll
    for (int cc = 0; cc < 4; ++cc) acc[r][cc] = B[colB + cc];
  tile_gemm(Sin, W, colB, rowB, acc);
#pragma unroll
  for (int r = 0; r < 4; ++r) {
    float4 v;
    v.x = acc[r][0]; v.y = acc[r][1]; v.z = acc[r][2]; v.w = acc[r][3];
    if (relu) { v.x = fmaxf(v.x, 0.f); v.y = fmaxf(v.y, 0.f); v.z = fmaxf(v.z, 0.f); v.w = fmaxf(v.w, 0.f); }
    *(float4*)&Sout[(rowB + r) * DIM + colB] = v;
  }
  __syncthreads();
}

__global__ __launch_bounds__(256) void vote_kernel(
    const float* __restrict__ X, int M,
    const float* __restrict__ W1, const float* __restrict__ b1,
    const float* __restrict__ W2, const float* __restrict__ b2,
    const float* __restrict__ W3, const float* __restrict__ b3,
    float* __restrict__ out) {
  __shared__ float Xs[32 * DIM];
  __shared__ float Ys[32 * DIM];
  int tid = threadIdx.x;
  int rb = blockIdx.x * 32;
  int mrows = M - rb; if (mrows > 32) mrows = 32;
  {
    const float4* src = (const float4*)(X + (size_t)rb * DIM);
    float4* dst = (float4*)Xs;
    int nf4 = mrows * (DIM / 4);
    for (int t = tid; t < 32 * (DIM / 4); t += 256) {
      float4 v;
      if (t < nf4) v = src[t];
      else { v.x = v.y = v.z = v.w = 0.f; }
      dst[t] = v;
    }
  }
  __syncthreads();
  int tx = tid & 31, ty = tid >> 5;
  int colB = tx * 4, rowB = ty * 4;
  layer_lds(Xs, Ys, W1, b1, true, colB, rowB);
  layer_lds(Ys, Xs, W2, b2, true, colB, rowB);
  if (tid < 32) {
    int gr = rb + tid;
    if (gr < M) {
      float s = b3[0];
      for (int k = 0; k < DIM; ++k) s += Xs[tid * DIM + k] * W3[k];
      out[gr] = s;
    }
  }
}

#define SZ128 (DIM * DIM)
#define SZ512 (4 * DIM * DIM)
#define O_CM1 0
#define O_CM2 (SZ128)
#define O_CM3 (2 * SZ128)
#define O_PM1 (3 * SZ128)
#define O_PM2 (4 * SZ128)
#define O_PM3 (5 * SZ128)
#define O_VUX ((size_t)6 * SZ128)
#define O_VUH ((size_t)6 * SZ128 + SZ512)
#define O_NUX ((size_t)6 * SZ128 + 2 * SZ512)
#define O_NUH ((size_t)6 * SZ128 + 3 * SZ512)

extern "C" void kernel_launch(void* const* d_in, const int* in_sizes, int n_in,
                              void* d_out, int out_size, void* d_ws, size_t ws_size,
                              hipStream_t stream) {
  const float* adj    = (const float*)d_in[0];
  const int*   values = (const int*)d_in[1];
  const int N       = in_sizes[1];                  // 9000
  const int n_nodes = in_sizes[0] / N;              // 8000
  const int n_vars  = N - n_nodes;                  // 1000

  const float* true_W  = (const float*)d_in[3];
  const float* true_b  = (const float*)d_in[4];
  const float* false_W = (const float*)d_in[5];
  const float* false_b = (const float*)d_in[6];
  const float* cm_W1 = (const float*)d_in[7];
  const float* cm_b1 = (const float*)d_in[8];
  const float* cm_W2 = (const float*)d_in[9];
  const float* cm_b2 = (const float*)d_in[10];
  const float* cm_W3 = (const float*)d_in[11];
  const float* cm_b3 = (const float*)d_in[12];
  const float* pm_W1 = (const float*)d_in[13];
  const float* pm_b1 = (const float*)d_in[14];
  const float* pm_W2 = (const float*)d_in[15];
  const float* pm_b2 = (const float*)d_in[16];
  const float* pm_W3 = (const float*)d_in[17];
  const float* pm_b3 = (const float*)d_in[18];
  const float* vv_W1 = (const float*)d_in[19];
  const float* vv_b1 = (const float*)d_in[20];
  const float* vv_W2 = (const float*)d_in[21];
  const float* vv_b2 = (const float*)d_in[22];
  const float* vv_W3 = (const float*)d_in[23];
  const float* vv_b3 = (const float*)d_in[24];
  const float* vu_Wih = (const float*)d_in[25];
  const float* vu_Whh = (const float*)d_in[26];
  const float* vu_bih = (const float*)d_in[27];
  const float* vu_bhh = (const float*)d_in[28];
  const float* nu_Wih = (const float*)d_in[29];
  const float* nu_Whh = (const float*)d_in[30];
  const float* nu_bih = (const float*)d_in[31];
  const float* nu_bhh = (const float*)d_in[32];

  uintptr_t p = (uintptr_t)d_ws;
  auto take = [&](size_t bytes) -> void* {
    uintptr_t cur = (p + 255) & ~(uintptr_t)255;
    p = cur + bytes;
    return (void*)cur;
  };
  float* h   = (float*)take((size_t)N * DIM * sizeof(float));
  float* cb  = (float*)take((size_t)N * DIM * sizeof(float));
  _Float16* va1 = (_Float16*)take((size_t)N * DIM * sizeof(_Float16));
  _Float16* va2 = (_Float16*)take((size_t)N * DIM * sizeof(_Float16));
  int* row_ptr = (int*)take((size_t)(n_nodes + 1) * sizeof(int));
  int* col_ptr = (int*)take((size_t)(N + 1) * sizeof(int));
  int* cnts    = (int*)take((size_t)(n_nodes + N) * sizeof(int));
  int* row_cnt = cnts;
  int* col_cnt = cnts + n_nodes;
  int* col_idx = (int*)take((size_t)NNZ_CAP * sizeof(int));
  int* row_idx = (int*)take((size_t)NNZ_CAP * sizeof(int));

  size_t tot_pack = (size_t)6 * SZ128 + (size_t)4 * SZ512;
  _Float16* packh = (_Float16*)take(tot_pack * sizeof(_Float16));
  float* vu_b = (float*)take(512 * sizeof(float));
  float* nu_b = (float*)take(512 * sizeof(float));

  hipMemsetAsync(cnts, 0, (size_t)(n_nodes + N) * sizeof(int), stream);
  dim3 cgrid(n_nodes, (N + 255) / 256);
  count_nz_kernel<<<cgrid, 256, 0, stream>>>(adj, row_cnt, col_cnt, N);
  scan_kernel<<<1, 256, 0, stream>>>(row_cnt, row_ptr, n_nodes);
  scan_kernel<<<1, 256, 0, stream>>>(col_cnt, col_ptr, N);
  fill_csr_kernel<<<n_nodes, 64, 0, stream>>>(adj, row_ptr, col_idx, N);
  fill_csc_kernel<<<(N + 63) / 64, 64, 0, stream>>>(adj, col_ptr, row_idx, n_nodes, N);
  init_hc_kernel<<<(N * DIM + 255) / 256, 256, 0, stream>>>(values, true_W, true_b,
                                                            false_W, false_b, h, cb, N);

  auto pack = [&](const float* src, int out_dim, size_t o) {
    pack_w_kernel<<<(out_dim * DIM + 255) / 256, 256, 0, stream>>>(src, out_dim, packh + o);
  };
  pack(cm_W1, DIM, O_CM1); pack(cm_W2, DIM, O_CM2); pack(cm_W3, DIM, O_CM3);
  pack(pm_W1, DIM, O_PM1); pack(pm_W2, DIM, O_PM2); pack(pm_W3, DIM, O_PM3);
  pack(vu_Wih, 4 * DIM, O_VUX); pack(vu_Whh, 4 * DIM, O_VUH);
  pack(nu_Wih, 4 * DIM, O_NUX); pack(nu_Whh, 4 * DIM, O_NUH);
  pack_bias_kernel<<<2, 256, 0, stream>>>(vu_bih, vu_bhh, vu_b, 512);
  pack_bias_kernel<<<2, 256, 0, stream>>>(nu_bih, nu_bhh, nu_b, 512);

  // grid <= 256 blocks per phase: one block per CU (no intra-dispatch CU tail)
  int rpbN = (N + 255) / 256;        // 36 for N=9000  -> NSUB=3 (48 slots)
  int gridN = (N + rpbN - 1) / rpbN; // 250
  int rpbn = (n_nodes + 255) / 256;        // 32 for 8000 -> NSUB=2
  int gridn = (n_nodes + rpbn - 1) / rpbn; // 250

  // A0: var_pre = cm_mlp(h) -> va1 (f16)
  mlp3_mfma<3><<<gridN, 512, 0, stream>>>(h, N, rpbN,
      packh + O_CM1, cm_b1, packh + O_CM2, cm_b2, packh + O_CM3, cm_b3, va1);

  for (int r = 0; r < NROUNDS; ++r) {
    // B+C: vu-LSTM(csr-gather va1) on rows<n_nodes, then pm-MLP(h_new) -> va2
    lstm_fused<2, true><<<gridn, 512, 0, stream>>>(row_ptr, col_idx, va1, h, cb, n_nodes, rpbn,
        packh + O_VUX, packh + O_VUH, vu_b,
        packh + O_PM1, pm_b1, packh + O_PM2, pm_b2, packh + O_PM3, pm_b3, va2);
    if (r + 1 < NROUNDS) {
      // D+A(next): nu-LSTM(csc-gather va2) on all N rows, then cm-MLP(h_new) -> va1
      lstm_fused<3, true><<<gridN, 512, 0, stream>>>(col_ptr, row_idx, va2, h, cb, N, rpbN,
          packh + O_NUX, packh + O_NUH, nu_b,
          packh + O_CM1, cm_b1, packh + O_CM2, cm_b2, packh + O_CM3, cm_b3, va1);
    } else {
      // final D: nu-LSTM only
      lstm_fused<3, false><<<gridN, 512, 0, stream>>>(col_ptr, row_idx, va2, h, cb, N, rpbN,
          packh + O_NUX, packh + O_NUH, nu_b,
          packh + O_CM1, cm_b1, packh + O_CM2, cm_b2, packh + O_CM3, cm_b3, va1);
    }
  }

  vote_kernel<<<(n_vars + 31) / 32, 256, 0, stream>>>(h + (size_t)n_nodes * DIM, n_vars,
      vv_W1, vv_b1, vv_W2, vv_b2, vv_W3, vv_b3, (float*)d_out);
}

// Round 12
// 10028.515 us; speedup vs baseline: 1.1823x; 1.0183x over previous
//
#include <hip/hip_runtime.h>
#include <cstddef>
#include <cstdint>

#define DIM 128
#define NROUNDS 120
#define NNZ_CAP (1 << 20)

typedef _Float16 half8 __attribute__((ext_vector_type(8)));
typedef float f32x4 __attribute__((ext_vector_type(4)));
typedef unsigned long long u64;

__device__ __forceinline__ float sigf(float x) { return 1.f / (1.f + __expf(-x)); }
__device__ __forceinline__ float tanh_fast(float x) { return 2.f / (1.f + __expf(-2.f * x)) - 1.f; }

// ---------------- sparse build (deterministic) ----------------
__global__ void count_nz_kernel(const float* __restrict__ adj, int* __restrict__ row_cnt,
                                int* __restrict__ col_cnt, int ncols) {
  int i = blockIdx.x;
  int j = blockIdx.y * blockDim.x + threadIdx.x;
  bool nz = (j < ncols) && (adj[(size_t)i * ncols + j] != 0.f);
  unsigned long long m = __ballot(nz);
  if ((threadIdx.x & 63) == 0) {
    int c = __popcll(m);
    if (c) atomicAdd(&row_cnt[i], c);
  }
  if (nz) atomicAdd(&col_cnt[j], 1);
}

__global__ void scan_kernel(const int* __restrict__ cnt, int* __restrict__ ptr, int n) {
  __shared__ int sdata[256];
  int t = threadIdx.x;
  int per = (n + 255) / 256;
  int beg = t * per;
  int end = beg + per; if (end > n) end = n;
  int local = 0;
  for (int i = beg; i < end; ++i) local += cnt[i];
  sdata[t] = local;
  __syncthreads();
  for (int off = 1; off < 256; off <<= 1) {
    int v = (t >= off) ? sdata[t - off] : 0;
    __syncthreads();
    sdata[t] += v;
    __syncthreads();
  }
  int run = sdata[t] - local;
  for (int i = beg; i < end; ++i) { ptr[i] = run; run += cnt[i]; }
  if (t == 255) ptr[n] = sdata[255];
}

__global__ __launch_bounds__(64) void fill_csr_kernel(const float* __restrict__ adj,
                                                      const int* __restrict__ row_ptr,
                                                      int* __restrict__ col_idx, int ncols) {
  int row = blockIdx.x;
  int lane = threadIdx.x;
  int base = row_ptr[row];
  int cursor = 0;
  const float* arow = adj + (size_t)row * ncols;
  for (int j0 = 0; j0 < ncols; j0 += 64) {
    int j = j0 + lane;
    bool nz = (j < ncols) && (arow[j] != 0.f);
    u64 m = __ballot(nz);
    int pre = __popcll(m & ((1ull << lane) - 1));
    if (nz) col_idx[base + cursor + pre] = j;
    cursor += __popcll(m);
  }
}

__global__ __launch_bounds__(64) void fill_csc_kernel(const float* __restrict__ adj,
                                                      const int* __restrict__ col_ptr,
                                                      int* __restrict__ row_idx,
                                                      int nrows, int ncols) {
  int c = blockIdx.x * 64 + threadIdx.x;
  if (c >= ncols) return;
  int cur = col_ptr[c];
  for (int i = 0; i < nrows; ++i) {
    if (adj[(size_t)i * ncols + c] != 0.f) row_idx[cur++] = i;
  }
}

// ---------------- weight packing: MFMA 16x16x32 B-fragment order (f16 only) ----------------
__global__ void pack_w_kernel(const float* __restrict__ src, int out_dim,
                              _Float16* __restrict__ dh) {
  int idx = blockIdx.x * 256 + threadIdx.x;
  if (idx >= out_dim * DIM) return;
  int n = idx >> 7, k = idx & 127;
  _Float16 hi = (_Float16)src[idx];
  int nt = n >> 4, ks = k >> 5;
  int L = ((k >> 3) & 3) * 16 + (n & 15);
  int j = k & 7;
  dh[((nt * 4 + ks) * 64 + L) * 8 + j] = hi;
}

__global__ void pack_bias_kernel(const float* __restrict__ a, const float* __restrict__ b,
                                 float* __restrict__ o, int n) {
  int i = blockIdx.x * 256 + threadIdx.x;
  if (i < n) o[i] = a[i] + b[i];
}

// ---------------- init ----------------
__global__ void init_hc_kernel(const int* __restrict__ values, const float* __restrict__ tW,
                               const float* __restrict__ tb, const float* __restrict__ fW,
                               const float* __restrict__ fb, float* __restrict__ h,
                               float* __restrict__ c, int N) {
  int idx = blockIdx.x * blockDim.x + threadIdx.x;
  if (idx >= N * DIM) return;
  int row = idx >> 7, col = idx & (DIM - 1);
  float tv = tW[col] + tb[col];
  float fv = fW[col] + fb[col];
  h[idx] = (values[row] == 1) ? tv : fv;
  c[idx] = 0.f;
}

// ---------------- LDS swizzle (rows x 128, 8-chunk XOR) ----------------
__device__ __forceinline__ int sw_idx(int m, int k) {
  return (m << 7) + (((((k >> 3) ^ (m & 15))) << 3) | (k & 7));
}

// L2-warm touch: issues independent line loads covering w[0..n) at 128B stride
__device__ __forceinline__ float touch(const _Float16* __restrict__ w, int n, int tid) {
  float t = 0.f;
  for (int i = tid * 64; i < n; i += 512 * 64) t += (float)w[i];
  return t;
}

// stage fp32 rows -> split f16 LDS (512 threads; NSUB*16 row slots)
template <int NSUB>
__device__ __forceinline__ void stage_rows_t(const float* __restrict__ src, int rend, int rb,
                                             _Float16* Sh, _Float16* Sl, int tid) {
  int seg = tid & 15;
  for (int r = tid >> 4; r < NSUB * 16; r += 32) {
    int row = rb + r;
    float4 v0, v1;
    if (row < rend) {
      const float4* s = (const float4*)(src + (size_t)row * DIM + seg * 8);
      v0 = s[0]; v1 = s[1];
    } else {
      v0.x = v0.y = v0.z = v0.w = 0.f; v1 = v0;
    }
    int a = sw_idx(r, seg * 8);
    float vv[8] = {v0.x, v0.y, v0.z, v0.w, v1.x, v1.y, v1.z, v1.w};
#pragma unroll
    for (int e = 0; e < 8; ++e) {
      _Float16 hi = (_Float16)vv[e];
      Sh[a + e] = hi;
      Sl[a + e] = (_Float16)(vv[e] - (float)hi);
    }
  }
}

// deterministic binary-SpMM gather (f16 va) -> split f16 LDS; 8-deep load unroll
template <int NSUB>
__device__ __forceinline__ void gather_rows_t(const int* __restrict__ ptr,
                                              const int* __restrict__ nzidx,
                                              const _Float16* __restrict__ va, int rend, int rb,
                                              _Float16* Xh, _Float16* Xl, int tid) {
  int seg = tid & 15;
  for (int r = tid >> 4; r < NSUB * 16; r += 32) {
    int row = rb + r;
    float a[8];
#pragma unroll
    for (int e = 0; e < 8; ++e) a[e] = 0.f;
    if (row < rend) {
      int s = ptr[row], e_ = ptr[row + 1];
      int p = s;
      for (; p + 8 <= e_; p += 8) {
        half8 v0 = *(const half8*)(va + (size_t)nzidx[p] * DIM + seg * 8);
        half8 v1 = *(const half8*)(va + (size_t)nzidx[p + 1] * DIM + seg * 8);
        half8 v2 = *(const half8*)(va + (size_t)nzidx[p + 2] * DIM + seg * 8);
        half8 v3 = *(const half8*)(va + (size_t)nzidx[p + 3] * DIM + seg * 8);
        half8 v4 = *(const half8*)(va + (size_t)nzidx[p + 4] * DIM + seg * 8);
        half8 v5 = *(const half8*)(va + (size_t)nzidx[p + 5] * DIM + seg * 8);
        half8 v6 = *(const half8*)(va + (size_t)nzidx[p + 6] * DIM + seg * 8);
        half8 v7 = *(const half8*)(va + (size_t)nzidx[p + 7] * DIM + seg * 8);
#pragma unroll
        for (int e = 0; e < 8; ++e)
          a[e] += (((float)v0[e] + (float)v1[e]) + ((float)v2[e] + (float)v3[e])) +
                  (((float)v4[e] + (float)v5[e]) + ((float)v6[e] + (float)v7[e]));
      }
      for (; p + 2 <= e_; p += 2) {
        half8 v0 = *(const half8*)(va + (size_t)nzidx[p] * DIM + seg * 8);
        half8 v1 = *(const half8*)(va + (size_t)nzidx[p + 1] * DIM + seg * 8);
#pragma unroll
        for (int e = 0; e < 8; ++e) a[e] += (float)v0[e] + (float)v1[e];
      }
      if (p < e_) {
        half8 v = *(const half8*)(va + (size_t)nzidx[p] * DIM + seg * 8);
#pragma unroll
        for (int e = 0; e < 8; ++e) a[e] += (float)v[e];
      }
    }
    int aoff = sw_idx(r, seg * 8);
#pragma unroll
    for (int e = 0; e < 8; ++e) {
      _Float16 hi = (_Float16)a[e];
      Xh[aoff + e] = hi;
      Xl[aoff + e] = (_Float16)(a[e] - (float)hi);
    }
  }
}

// split-A x f16-B: 2 MFMAs per product
__device__ __forceinline__ void mfma2(f32x4& acc, half8 ah, half8 al, half8 bh) {
  acc = __builtin_amdgcn_mfma_f32_16x16x32_f16(ah, bh, acc, 0, 0, 0);
  acc = __builtin_amdgcn_mfma_f32_16x16x32_f16(al, bh, acc, 0, 0, 0);
}

// one MLP layer: NSUB 16-row subtiles, 8 waves; wave w owns col tile w (16 cols)
template <int NSUB>
__device__ __forceinline__ void mlp_layer_t(const _Float16* Ah_, const _Float16* Al_,
                                            const _Float16* __restrict__ Wh,
                                            const float* __restrict__ B,
                                            _Float16* Dh, _Float16* Dl, int tid) {
  int lane = tid & 63, w = tid >> 6;
  int m16 = lane & 15, quad = lane >> 4;
  float bv = B[w * 16 + m16];
  f32x4 acc[NSUB];
#pragma unroll
  for (int s = 0; s < NSUB; ++s) acc[s] = (f32x4){bv, bv, bv, bv};
#pragma unroll
  for (int ks = 0; ks < 4; ++ks) {
    int boff = ((w * 4 + ks) * 64 + lane) * 8;
    half8 bh = *(const half8*)(Wh + boff);
#pragma unroll
    for (int s = 0; s < NSUB; ++s) {
      int a_off = sw_idx(s * 16 + m16, ks * 32 + quad * 8);
      mfma2(acc[s], *(const half8*)(Ah_ + a_off), *(const half8*)(Al_ + a_off), bh);
    }
  }
#pragma unroll
  for (int s = 0; s < NSUB; ++s)
#pragma unroll
    for (int reg = 0; reg < 4; ++reg) {
      int rl = s * 16 + quad * 4 + reg;
      int col = w * 16 + m16;
      float x = fmaxf(acc[s][reg], 0.f);
      _Float16 hi = (_Float16)x;
      int a = sw_idx(rl, col);
      Dh[a] = hi;
      Dl[a] = (_Float16)(x - (float)hi);
    }
  __syncthreads();
}

// full 3-layer MLP from LDS input S0/S1; scratch S2/S3; final -> f16 global
template <int NSUB>
__device__ __forceinline__ void mlp_from_lds_t(
    _Float16* S0, _Float16* S1, _Float16* S2, _Float16* S3, int rend, int rb,
    const _Float16* __restrict__ W1h, const float* __restrict__ b1,
    const _Float16* __restrict__ W2h, const float* __restrict__ b2,
    const _Float16* __restrict__ W3h, const float* __restrict__ b3,
    _Float16* __restrict__ out) {
  int tid = threadIdx.x;
  mlp_layer_t<NSUB>(S0, S1, W1h, b1, S2, S3, tid);
  mlp_layer_t<NSUB>(S2, S3, W2h, b2, S0, S1, tid);
  int lane = tid & 63, w = tid >> 6;
  int m16 = lane & 15, quad = lane >> 4;
  float bv = b3[w * 16 + m16];
  f32x4 acc[NSUB];
#pragma unroll
  for (int s = 0; s < NSUB; ++s) acc[s] = (f32x4){bv, bv, bv, bv};
#pragma unroll
  for (int ks = 0; ks < 4; ++ks) {
    int boff = ((w * 4 + ks) * 64 + lane) * 8;
    half8 bh = *(const half8*)(W3h + boff);
#pragma unroll
    for (int s = 0; s < NSUB; ++s) {
      int a_off = sw_idx(s * 16 + m16, ks * 32 + quad * 8);
      mfma2(acc[s], *(const half8*)(S0 + a_off), *(const half8*)(S1 + a_off), bh);
    }
  }
#pragma unroll
  for (int s = 0; s < NSUB; ++s)
#pragma unroll
    for (int reg = 0; reg < 4; ++reg) {
      int row = rb + s * 16 + quad * 4 + reg;
      int col = w * 16 + m16;
      if (row < rend) out[(size_t)row * DIM + col] = (_Float16)acc[s][reg];
    }
}

// ---------------- standalone MLP (initial phase A): global h -> f16 va ----------------
template <int NSUB>
__global__ __launch_bounds__(512, 4) void mlp3_mfma(
    const float* __restrict__ X, int M, int rpb,
    const _Float16* __restrict__ W1h, const float* __restrict__ b1,
    const _Float16* __restrict__ W2h, const float* __restrict__ b2,
    const _Float16* __restrict__ W3h, const float* __restrict__ b3,
    _Float16* __restrict__ out) {
  __shared__ _Float16 S0[NSUB * 2048], S1[NSUB * 2048], S2[NSUB * 2048], S3[NSUB * 2048];
  int tid = threadIdx.x;
  int rb = blockIdx.x * rpb;
  int rend = rb + rpb; if (rend > M) rend = M;
  float tpf = touch(W1h, DIM * DIM, tid) + touch(W2h, DIM * DIM, tid) + touch(W3h, DIM * DIM, tid);
  stage_rows_t<NSUB>(X, rend, rb, S0, S1, tid);
  asm volatile("" :: "v"(tpf));
  __syncthreads();
  mlp_from_lds_t<NSUB>(S0, S1, S2, S3, rend, rb, W1h, b1, W2h, b2, W3h, b3, out);
}

// ---------------- fused LSTM (+ optional row-local MLP) ----------------
// 512 threads, NSUB*16 row slots (rpb active rows); wave w owns cols [w*16,w*16+16) per gate
template <int NSUB, bool DO_MLP>
__global__ __launch_bounds__(512, 4) void lstm_fused(
    const int* __restrict__ ptr, const int* __restrict__ nzidx, const _Float16* __restrict__ va_in,
    float* __restrict__ hbuf, float* __restrict__ cbuf, int M, int rpb,
    const _Float16* __restrict__ Wxh, const _Float16* __restrict__ Whh_,
    const float* __restrict__ bcomb,
    const _Float16* __restrict__ W1h, const float* __restrict__ b1,
    const _Float16* __restrict__ W2h, const float* __restrict__ b2,
    const _Float16* __restrict__ W3h, const float* __restrict__ b3,
    _Float16* __restrict__ va_out) {
  __shared__ _Float16 Xh[NSUB * 2048], Xl[NSUB * 2048], Hh[NSUB * 2048], Hl[NSUB * 2048];
  int tid = threadIdx.x;
  int rb = blockIdx.x * rpb;
  int rend = rb + rpb; if (rend > M) rend = M;

  // L2-warm the weight streams (independent loads, overlap with stage/gather latency)
  float tpf = touch(Wxh, 4 * DIM * DIM, tid) + touch(Whh_, 4 * DIM * DIM, tid) +
              touch(W1h, DIM * DIM, tid) + touch(W2h, DIM * DIM, tid) + touch(W3h, DIM * DIM, tid);

  stage_rows_t<NSUB>(hbuf, rend, rb, Hh, Hl, tid);
  gather_rows_t<NSUB>(ptr, nzidx, va_in, rend, rb, Xh, Xl, tid);

  int lane = tid & 63, w = tid >> 6;
  int m16 = lane & 15, quad = lane >> 4;

  // prefetch old c (epilogue operand) early
  float cold[NSUB][4];
#pragma unroll
  for (int s = 0; s < NSUB; ++s)
#pragma unroll
    for (int reg = 0; reg < 4; ++reg) {
      int row = rb + s * 16 + quad * 4 + reg;
      cold[s][reg] = (row < rend) ? cbuf[(size_t)row * DIM + w * 16 + m16] : 0.f;
    }
  asm volatile("" :: "v"(tpf));
  __syncthreads();

  f32x4 acc[NSUB][4];
#pragma unroll
  for (int g = 0; g < 4; ++g) {
    float bv = bcomb[g * 128 + w * 16 + m16];
#pragma unroll
    for (int s = 0; s < NSUB; ++s) acc[s][g] = (f32x4){bv, bv, bv, bv};
  }
  // H @ Whh^T (B fragment loaded once, applied to all subtiles)
#pragma unroll
  for (int ks = 0; ks < 4; ++ks) {
#pragma unroll
    for (int g = 0; g < 4; ++g) {
      int ct = g * 8 + w;
      int boff = ((ct * 4 + ks) * 64 + lane) * 8;
      half8 bh = *(const half8*)(Whh_ + boff);
#pragma unroll
      for (int s = 0; s < NSUB; ++s) {
        int a_off = sw_idx(s * 16 + m16, ks * 32 + quad * 8);
        mfma2(acc[s][g], *(const half8*)(Hh + a_off), *(const half8*)(Hl + a_off), bh);
      }
    }
  }
  // X @ Wih^T
#pragma unroll
  for (int ks = 0; ks < 4; ++ks) {
#pragma unroll
    for (int g = 0; g < 4; ++g) {
      int ct = g * 8 + w;
      int boff = ((ct * 4 + ks) * 64 + lane) * 8;
      half8 bh = *(const half8*)(Wxh + boff);
#pragma unroll
      for (int s = 0; s < NSUB; ++s) {
        int a_off = sw_idx(s * 16 + m16, ks * 32 + quad * 8);
        mfma2(acc[s][g], *(const half8*)(Xh + a_off), *(const half8*)(Xl + a_off), bh);
      }
    }
  }

  if (DO_MLP) __syncthreads();  // all waves done reading Xh/Xl/Hh/Hl before overwrite

  // elementwise epilogue (gate order i,f,g,o); h,c -> global; h_new -> LDS (A-layout)
#pragma unroll
  for (int s = 0; s < NSUB; ++s)
#pragma unroll
    for (int reg = 0; reg < 4; ++reg) {
      int rl = s * 16 + quad * 4 + reg;
      int row = rb + rl;
      int col = w * 16 + m16;
      float hn = 0.f;
      if (row < rend) {
        float iv = sigf(acc[s][0][reg]);
        float fv = sigf(acc[s][1][reg]);
        float gv = tanh_fast(acc[s][2][reg]);
        float ov = sigf(acc[s][3][reg]);
        size_t o = (size_t)row * DIM + col;
        float cn = fv * cold[s][reg] + iv * gv;
        cbuf[o] = cn;
        hn = ov * tanh_fast(cn);
        hbuf[o] = hn;
      }
      if (DO_MLP) {
        int a = sw_idx(rl, col);
        _Float16 hi = (_Float16)hn;
        Xh[a] = hi;
        Xl[a] = (_Float16)(hn - (float)hi);
      }
    }
  if (DO_MLP) {
    __syncthreads();
    mlp_from_lds_t<NSUB>(Xh, Xl, Hh, Hl, rend, rb, W1h, b1, W2h, b2, W3h, b3, va_out);
  }
}

// ---------------- final vote MLP (fp32, runs once) ----------------
__device__ __forceinline__ void tile_gemm(const float* S, const float* __restrict__ W,
                                          int colB, int rowB, float acc[4][4]) {
#pragma unroll 4
  for (int kc = 0; kc < DIM; kc += 4) {
    float4 xv[4], wv[4];
#pragma unroll
    for (int r = 0; r < 4; ++r) xv[r] = *(const float4*)(S + (rowB + r) * DIM + kc);
#pragma unroll
    for (int c = 0; c < 4; ++c) wv[c] = *(const float4*)(W + (size_t)(colB + c) * DIM + kc);
#pragma unroll
    for (int r = 0; r < 4; ++r)
#pragma unroll
      for (int c = 0; c < 4; ++c)
        acc[r][c] += xv[r].x * wv[c].x + xv[r].y * wv[c].y + xv[r].z * wv[c].z + xv[r].w * wv[c].w;
  }
}

__device__ __forceinline__ void layer_lds(const float* Sin, float* Sout,
                                          const float* __restrict__ W, const float* __restrict__ B,
                                          bool relu, int colB, int rowB) {
  float acc[4][4];
#pragma unroll
  for (int r = 0; r < 4; ++r)
#pragma unroll
    for (int cc = 0; cc < 4; ++cc) acc[r][cc] = B[colB + cc];
  tile_gemm(Sin, W, colB, rowB, acc);
#pragma unroll
  for (int r = 0; r < 4; ++r) {
    float4 v;
    v.x = acc[r][0]; v.y = acc[r][1]; v.z = acc[r][2]; v.w = acc[r][3];
    if (relu) { v.x = fmaxf(v.x, 0.f); v.y = fmaxf(v.y, 0.f); v.z = fmaxf(v.z, 0.f); v.w = fmaxf(v.w, 0.f); }
    *(float4*)&Sout[(rowB + r) * DIM + colB] = v;
  }
  __syncthreads();
}

__global__ __launch_bounds__(256) void vote_kernel(
    const float* __restrict__ X, int M,
    const float* __restrict__ W1, const float* __restrict__ b1,
    const float* __restrict__ W2, const float* __restrict__ b2,
    const float* __restrict__ W3, const float* __restrict__ b3,
    float* __restrict__ out) {
  __shared__ float Xs[32 * DIM];
  __shared__ float Ys[32 * DIM];
  int tid = threadIdx.x;
  int rb = blockIdx.x * 32;
  int mrows = M - rb; if (mrows > 32) mrows = 32;
  {
    const float4* src = (const float4*)(X + (size_t)rb * DIM);
    float4* dst = (float4*)Xs;
    int nf4 = mrows * (DIM / 4);
    for (int t = tid; t < 32 * (DIM / 4); t += 256) {
      float4 v;
      if (t < nf4) v = src[t];
      else { v.x = v.y = v.z = v.w = 0.f; }
      dst[t] = v;
    }
  }
  __syncthreads();
  int tx = tid & 31, ty = tid >> 5;
  int colB = tx * 4, rowB = ty * 4;
  layer_lds(Xs, Ys, W1, b1, true, colB, rowB);
  layer_lds(Ys, Xs, W2, b2, true, colB, rowB);
  if (tid < 32) {
    int gr = rb + tid;
    if (gr < M) {
      float s = b3[0];
      for (int k = 0; k < DIM; ++k) s += Xs[tid * DIM + k] * W3[k];
      out[gr] = s;
    }
  }
}

#define SZ128 (DIM * DIM)
#define SZ512 (4 * DIM * DIM)
#define O_CM1 0
#define O_CM2 (SZ128)
#define O_CM3 (2 * SZ128)
#define O_PM1 (3 * SZ128)
#define O_PM2 (4 * SZ128)
#define O_PM3 (5 * SZ128)
#define O_VUX ((size_t)6 * SZ128)
#define O_VUH ((size_t)6 * SZ128 + SZ512)
#define O_NUX ((size_t)6 * SZ128 + 2 * SZ512)
#define O_NUH ((size_t)6 * SZ128 + 3 * SZ512)

extern "C" void kernel_launch(void* const* d_in, const int* in_sizes, int n_in,
                              void* d_out, int out_size, void* d_ws, size_t ws_size,
                              hipStream_t stream) {
  const float* adj    = (const float*)d_in[0];
  const int*   values = (const int*)d_in[1];
  const int N       = in_sizes[1];                  // 9000
  const int n_nodes = in_sizes[0] / N;              // 8000
  const int n_vars  = N - n_nodes;                  // 1000

  const float* true_W  = (const float*)d_in[3];
  const float* true_b  = (const float*)d_in[4];
  const float* false_W = (const float*)d_in[5];
  const float* false_b = (const float*)d_in[6];
  const float* cm_W1 = (const float*)d_in[7];
  const float* cm_b1 = (const float*)d_in[8];
  const float* cm_W2 = (const float*)d_in[9];
  const float* cm_b2 = (const float*)d_in[10];
  const float* cm_W3 = (const float*)d_in[11];
  const float* cm_b3 = (const float*)d_in[12];
  const float* pm_W1 = (const float*)d_in[13];
  const float* pm_b1 = (const float*)d_in[14];
  const float* pm_W2 = (const float*)d_in[15];
  const float* pm_b2 = (const float*)d_in[16];
  const float* pm_W3 = (const float*)d_in[17];
  const float* pm_b3 = (const float*)d_in[18];
  const float* vv_W1 = (const float*)d_in[19];
  const float* vv_b1 = (const float*)d_in[20];
  const float* vv_W2 = (const float*)d_in[21];
  const float* vv_b2 = (const float*)d_in[22];
  const float* vv_W3 = (const float*)d_in[23];
  const float* vv_b3 = (const float*)d_in[24];
  const float* vu_Wih = (const float*)d_in[25];
  const float* vu_Whh = (const float*)d_in[26];
  const float* vu_bih = (const float*)d_in[27];
  const float* vu_bhh = (const float*)d_in[28];
  const float* nu_Wih = (const float*)d_in[29];
  const float* nu_Whh = (const float*)d_in[30];
  const float* nu_bih = (const float*)d_in[31];
  const float* nu_bhh = (const float*)d_in[32];

  uintptr_t p = (uintptr_t)d_ws;
  auto take = [&](size_t bytes) -> void* {
    uintptr_t cur = (p + 255) & ~(uintptr_t)255;
    p = cur + bytes;
    return (void*)cur;
  };
  float* h   = (float*)take((size_t)N * DIM * sizeof(float));
  float* cb  = (float*)take((size_t)N * DIM * sizeof(float));
  _Float16* va1 = (_Float16*)take((size_t)N * DIM * sizeof(_Float16));
  _Float16* va2 = (_Float16*)take((size_t)N * DIM * sizeof(_Float16));
  int* row_ptr = (int*)take((size_t)(n_nodes + 1) * sizeof(int));
  int* col_ptr = (int*)take((size_t)(N + 1) * sizeof(int));
  int* cnts    = (int*)take((size_t)(n_nodes + N) * sizeof(int));
  int* row_cnt = cnts;
  int* col_cnt = cnts + n_nodes;
  int* col_idx = (int*)take((size_t)NNZ_CAP * sizeof(int));
  int* row_idx = (int*)take((size_t)NNZ_CAP * sizeof(int));

  size_t tot_pack = (size_t)6 * SZ128 + (size_t)4 * SZ512;
  _Float16* packh = (_Float16*)take(tot_pack * sizeof(_Float16));
  float* vu_b = (float*)take(512 * sizeof(float));
  float* nu_b = (float*)take(512 * sizeof(float));

  hipMemsetAsync(cnts, 0, (size_t)(n_nodes + N) * sizeof(int), stream);
  dim3 cgrid(n_nodes, (N + 255) / 256);
  count_nz_kernel<<<cgrid, 256, 0, stream>>>(adj, row_cnt, col_cnt, N);
  scan_kernel<<<1, 256, 0, stream>>>(row_cnt, row_ptr, n_nodes);
  scan_kernel<<<1, 256, 0, stream>>>(col_cnt, col_ptr, N);
  fill_csr_kernel<<<n_nodes, 64, 0, stream>>>(adj, row_ptr, col_idx, N);
  fill_csc_kernel<<<(N + 63) / 64, 64, 0, stream>>>(adj, col_ptr, row_idx, n_nodes, N);
  init_hc_kernel<<<(N * DIM + 255) / 256, 256, 0, stream>>>(values, true_W, true_b,
                                                            false_W, false_b, h, cb, N);

  auto pack = [&](const float* src, int out_dim, size_t o) {
    pack_w_kernel<<<(out_dim * DIM + 255) / 256, 256, 0, stream>>>(src, out_dim, packh + o);
  };
  pack(cm_W1, DIM, O_CM1); pack(cm_W2, DIM, O_CM2); pack(cm_W3, DIM, O_CM3);
  pack(pm_W1, DIM, O_PM1); pack(pm_W2, DIM, O_PM2); pack(pm_W3, DIM, O_PM3);
  pack(vu_Wih, 4 * DIM, O_VUX); pack(vu_Whh, 4 * DIM, O_VUH);
  pack(nu_Wih, 4 * DIM, O_NUX); pack(nu_Whh, 4 * DIM, O_NUH);
  pack_bias_kernel<<<2, 256, 0, stream>>>(vu_bih, vu_bhh, vu_b, 512);
  pack_bias_kernel<<<2, 256, 0, stream>>>(nu_bih, nu_bhh, nu_b, 512);

  // 2 co-resident blocks/CU: grid 500, 16 waves/CU (2x outstanding misses)
  int rpbN = (N + 499) / 500;        // 18 -> NSUB=2 (32 slots)
  int gridN = (N + rpbN - 1) / rpbN; // 500
  int rpbn = (n_nodes + 499) / 500;        // 16 -> NSUB=1
  int gridn = (n_nodes + rpbn - 1) / rpbn; // 500

  // A0: var_pre = cm_mlp(h) -> va1 (f16)
  mlp3_mfma<2><<<gridN, 512, 0, stream>>>(h, N, rpbN,
      packh + O_CM1, cm_b1, packh + O_CM2, cm_b2, packh + O_CM3, cm_b3, va1);

  for (int r = 0; r < NROUNDS; ++r) {
    // B+C: vu-LSTM(csr-gather va1) on rows<n_nodes, then pm-MLP(h_new) -> va2
    lstm_fused<1, true><<<gridn, 512, 0, stream>>>(row_ptr, col_idx, va1, h, cb, n_nodes, rpbn,
        packh + O_VUX, packh + O_VUH, vu_b,
        packh + O_PM1, pm_b1, packh + O_PM2, pm_b2, packh + O_PM3, pm_b3, va2);
    if (r + 1 < NROUNDS) {
      // D+A(next): nu-LSTM(csc-gather va2) on all N rows, then cm-MLP(h_new) -> va1
      lstm_fused<2, true><<<gridN, 512, 0, stream>>>(col_ptr, row_idx, va2, h, cb, N, rpbN,
          packh + O_NUX, packh + O_NUH, nu_b,
          packh + O_CM1, cm_b1, packh + O_CM2, cm_b2, packh + O_CM3, cm_b3, va1);
    } else {
      // final D: nu-LSTM only
      lstm_fused<2, false><<<gridN, 512, 0, stream>>>(col_ptr, row_idx, va2, h, cb, N, rpbN,
          packh + O_NUX, packh + O_NUH, nu_b,
          packh + O_CM1, cm_b1, packh + O_CM2, cm_b2, packh + O_CM3, cm_b3, va1);
    }
  }

  vote_kernel<<<(n_vars + 31) / 32, 256, 0, stream>>>(h + (size_t)n_nodes * DIM, n_vars,
      vv_W1, vv_b1, vv_W2, vv_b2, vv_W3, vv_b3, (float*)d_out);
}